// Round 1
// baseline (303.950 us; speedup 1.0000x reference)
//
#include <hip/hip_runtime.h>

#define Bn 2
#define Cn 512
#define Ln 4096
#define Hn 8
#define Dn 64

typedef _Float16 f16;
typedef _Float16 h8 __attribute__((ext_vector_type(8)));
typedef _Float16 h4 __attribute__((ext_vector_type(4)));
typedef float f32x4 __attribute__((ext_vector_type(4)));

// ---------------- kernel 1: X [B][C][L] f32 -> Xt [B][L][C] f16 ----------------
__global__ __launch_bounds__(256) void k_transpose(const float* __restrict__ X,
                                                   f16* __restrict__ Xt) {
  int bid = blockIdx.x;
  int b  = bid >> 9;            // 512 tiles per batch
  int r  = bid & 511;
  int lt = r >> 3, ct = r & 7;  // 64 l-tiles x 8 c-tiles
  int l0 = lt << 6, c0 = ct << 6;
  __shared__ f16 t[64][66];     // pad 2 f16 -> row stride 33 dwords (odd): 2-way max
  int tid = threadIdx.x;
  int lx = tid & 63, cg = tid >> 6;
  const float* xb = X + ((size_t)b * Cn) * Ln;
#pragma unroll
  for (int rr = 0; rr < 16; ++rr) {
    int cl = cg * 16 + rr;
    t[lx][cl] = (f16)xb[(size_t)(c0 + cl) * Ln + l0 + lx];   // coalesced over l
  }
  __syncthreads();
  f16* xo = Xt + ((size_t)b * Ln + l0) * Cn + c0;
  int cx = tid & 63, lg = tid >> 6;
#pragma unroll
  for (int rr = 0; rr < 16; ++rr) {
    int ll = lg * 16 + rr;
    xo[(size_t)ll * Cn + cx] = t[ll][cx];                    // coalesced over c
  }
}

// ---------------- kernel 2: projection GEMM ----------------
// C[o][l] = sum_c Wcat[o][c] * Xt[l][c], per batch. M=1536, N=4096, K=512.
// rows 0..511 -> Q (scaled, [B,H,L,D]), 512..1023 -> K ([B,H,L,D]), 1024..1535 -> V ([B,C,L])
__global__ __launch_bounds__(256) void k_proj(const float* __restrict__ Wq,
                                              const float* __restrict__ Wm,
                                              const f16* __restrict__ Xt,
                                              f16* __restrict__ Qd,
                                              f16* __restrict__ Kd,
                                              f16* __restrict__ Vv) {
  int bid = blockIdx.x;            // 2 * 12 * 32 = 768
  int b = bid / 384;
  int r = bid % 384;
  int mt = r >> 5, nt = r & 31;
  int o0 = mt << 7, l0 = nt << 7;
  __shared__ f16 a_lds[128][40];   // +8 f16 pad: 20-dword stride, 2-way max on b128
  __shared__ f16 b_lds[128][40];
  int tid = threadIdx.x;
  int lane = tid & 63, w = tid >> 6;
  int wr = w >> 1, wc = w & 1;     // 2x2 wave grid, 64x64 per wave
  f32x4 acc[4][4] = {};

  int sr = tid >> 1;               // staging row 0..127
  int scg = (tid & 1) << 4;        // col group 0 / 16
  int o_s = o0 + sr;
  const float* wrow = (o_s < 512) ? (Wq + (size_t)o_s * Cn)
                                  : (Wm + (size_t)(o_s - 512) * Cn);
  const f16* xrow = Xt + ((size_t)b * Ln + l0 + sr) * Cn;

  for (int kt = 0; kt < 16; ++kt) {
    int c0 = kt << 5;
    __syncthreads();
#pragma unroll
    for (int i = 0; i < 4; ++i) {
      float4 w4 = *(const float4*)(wrow + c0 + scg + 4 * i);
      h4 hh = { (f16)w4.x, (f16)w4.y, (f16)w4.z, (f16)w4.w };
      *(h4*)&a_lds[sr][scg + 4 * i] = hh;
    }
#pragma unroll
    for (int i = 0; i < 2; ++i)
      *(h8*)&b_lds[sr][scg + 8 * i] = *(const h8*)(xrow + c0 + scg + 8 * i);
    __syncthreads();

    h8 af[4], bf[4];
#pragma unroll
    for (int mi = 0; mi < 4; ++mi)
      af[mi] = *(const h8*)&a_lds[wr * 64 + mi * 16 + (lane & 15)][(lane >> 4) * 8];
#pragma unroll
    for (int ni = 0; ni < 4; ++ni)
      bf[ni] = *(const h8*)&b_lds[wc * 64 + ni * 16 + (lane & 15)][(lane >> 4) * 8];
#pragma unroll
    for (int mi = 0; mi < 4; ++mi)
#pragma unroll
      for (int ni = 0; ni < 4; ++ni)
        acc[mi][ni] = __builtin_amdgcn_mfma_f32_16x16x32_f16(af[mi], bf[ni], acc[mi][ni], 0, 0, 0);
  }

  const float QSCALE = 0.18033688011112042f;   // 2^-3 * log2(e): base-2 softmax
  int lrow = (lane >> 4) << 2;
  int lcol = lane & 15;
#pragma unroll
  for (int mi = 0; mi < 4; ++mi) {
    int ob = o0 + wr * 64 + mi * 16 + lrow;    // o for acc reg 0 (regs = consecutive o)
#pragma unroll
    for (int ni = 0; ni < 4; ++ni) {
      int lc = l0 + wc * 64 + ni * 16 + lcol;
      f32x4 a = acc[mi][ni];
      if (ob < 512) {
        int h = ob >> 6, d = ob & 63;
        h4 hh = { (f16)(a[0] * QSCALE), (f16)(a[1] * QSCALE),
                  (f16)(a[2] * QSCALE), (f16)(a[3] * QSCALE) };
        *(h4*)&Qd[(((size_t)b * Hn + h) * Ln + lc) * Dn + d] = hh;
      } else if (ob < 1024) {
        int oc = ob - 512;
        int h = oc >> 6, d = oc & 63;
        h4 hh = { (f16)a[0], (f16)a[1], (f16)a[2], (f16)a[3] };
        *(h4*)&Kd[(((size_t)b * Hn + h) * Ln + lc) * Dn + d] = hh;
      } else {
        int oc = ob - 1024;
#pragma unroll
        for (int rr = 0; rr < 4; ++rr)
          Vv[((size_t)b * Cn + oc + rr) * Ln + lc] = (f16)a[rr];
      }
    }
  }
}

// ---------------- kernel 3: flash attention ----------------
// grid: 16 (b,h) x 64 i-blocks. Block = 4 waves; wave owns 16 q-rows; BN=64 keys/step.
__global__ __launch_bounds__(256) void k_attn(const f16* __restrict__ Qd,
                                              const f16* __restrict__ Kd,
                                              const f16* __restrict__ Vv,
                                              const int* __restrict__ mask,
                                              float* __restrict__ out) {
  int bid = blockIdx.x;
  int bh = bid >> 6;
  int ib = bid & 63;
  int b = bh >> 3, h = bh & 7;
  int tid = threadIdx.x;
  int lane = tid & 63, w = tid >> 6;
  // rows are 128B (8 x 16B chunks); physical chunk = chunk ^ (row&7)  [G4 swizzle]
  __shared__ f16 k_lds[64 * 64];
  __shared__ f16 v_lds[64 * 64];
  __shared__ f16 p_lds[4][16 * 64];

  int i_loc = lane & 15;
  int g = lane >> 4;
  const h8* qsrc = (const h8*)(Qd + (((size_t)bh) * Ln + ib * 64 + w * 16 + i_loc) * Dn);
  h8 aq0 = qsrc[g];        // A-frag kk=0: d = g*8..+7
  h8 aq1 = qsrc[4 + g];    // kk=1: d = 32 + g*8..

  f32x4 acc[4] = {};
  float mrow[4] = { -1e38f, -1e38f, -1e38f, -1e38f };
  float lsum[4] = { 0.f, 0.f, 0.f, 0.f };

  int srow = tid >> 2;
  int sc0 = tid & 3;
  const f16* kbase = Kd + ((size_t)bh * Ln) * Dn;
  const f16* vbase = Vv + ((size_t)b * Cn + h * 64) * Ln;
  const int* mbase = mask + (size_t)b * Ln;

  for (int jb = 0; jb < 64; ++jb) {
    __syncthreads();
    {  // stage K tile [64 j][64 d] and V tile [64 d][64 j], swizzled
      const h8* src = (const h8*)(kbase + (size_t)(jb * 64 + srow) * Dn);
#pragma unroll
      for (int cc = sc0; cc < 8; cc += 4)
        *(h8*)&k_lds[srow * 64 + ((cc ^ (srow & 7)) << 3)] = src[cc];
      const f16* vsrc = vbase + (size_t)srow * Ln + jb * 64;
#pragma unroll
      for (int cc = sc0; cc < 8; cc += 4)
        *(h8*)&v_lds[srow * 64 + ((cc ^ (srow & 7)) << 3)] = *(const h8*)(vsrc + cc * 8);
    }
    __syncthreads();

    // S = Q K^T : 4 j-tiles of 16
    f32x4 s[4];
#pragma unroll
    for (int jt = 0; jt < 4; ++jt) {
      int j = jt * 16 + i_loc;
      f32x4 z = {};
      h8 bk0 = *(const h8*)&k_lds[j * 64 + ((g ^ (lane & 7)) << 3)];
      z = __builtin_amdgcn_mfma_f32_16x16x32_f16(aq0, bk0, z, 0, 0, 0);
      h8 bk1 = *(const h8*)&k_lds[j * 64 + (((4 + g) ^ (lane & 7)) << 3)];
      z = __builtin_amdgcn_mfma_f32_16x16x32_f16(aq1, bk1, z, 0, 0, 0);
      int mk = mbase[jb * 64 + j];
      float madd = mk ? 0.f : -1e30f;
      z[0] += madd; z[1] += madd; z[2] += madd; z[3] += madd;
      s[jt] = z;
    }

    // online softmax (base-2; scale folded into Q)
    float al[4];
#pragma unroll
    for (int rr = 0; rr < 4; ++rr) {
      float m0 = fmaxf(fmaxf(s[0][rr], s[1][rr]), fmaxf(s[2][rr], s[3][rr]));
#pragma unroll
      for (int off = 1; off < 16; off <<= 1)
        m0 = fmaxf(m0, __shfl_xor(m0, off));
      float mn = fmaxf(mrow[rr], m0);
      al[rr] = (mrow[rr] > -1e37f) ? exp2f(mrow[rr] - mn) : 0.f;
      mrow[rr] = mn;
    }
    float p[4][4];
#pragma unroll
    for (int jt = 0; jt < 4; ++jt)
#pragma unroll
      for (int rr = 0; rr < 4; ++rr)
        p[jt][rr] = exp2f(s[jt][rr] - mrow[rr]);
#pragma unroll
    for (int rr = 0; rr < 4; ++rr) {
      float t0 = p[0][rr] + p[1][rr] + p[2][rr] + p[3][rr];
#pragma unroll
      for (int off = 1; off < 16; off <<= 1)
        t0 += __shfl_xor(t0, off);
      lsum[rr] = lsum[rr] * al[rr] + t0;
    }
#pragma unroll
    for (int t = 0; t < 4; ++t) {
      f32x4 a = acc[t];
      a[0] *= al[0]; a[1] *= al[1]; a[2] *= al[2]; a[3] *= al[3];
      acc[t] = a;
    }

    // P -> per-wave LDS (f16), swizzled like K/V tiles
    f16* pw = p_lds[w];
#pragma unroll
    for (int jt = 0; jt < 4; ++jt) {
      int j = jt * 16 + i_loc;
#pragma unroll
      for (int rr = 0; rr < 4; ++rr) {
        int i = g * 4 + rr;
        pw[i * 64 + (((j >> 3) ^ (i & 7)) << 3) + (j & 7)] = (f16)p[jt][rr];
      }
    }

    // O += P V
    h8 pa0 = *(const h8*)&pw[i_loc * 64 + ((g ^ (i_loc & 7)) << 3)];
    h8 pa1 = *(const h8*)&pw[i_loc * 64 + (((4 + g) ^ (i_loc & 7)) << 3)];
#pragma unroll
    for (int t = 0; t < 4; ++t) {
      int d = t * 16 + i_loc;
      h8 vb0 = *(const h8*)&v_lds[d * 64 + ((g ^ (lane & 7)) << 3)];
      acc[t] = __builtin_amdgcn_mfma_f32_16x16x32_f16(pa0, vb0, acc[t], 0, 0, 0);
      h8 vb1 = *(const h8*)&v_lds[d * 64 + (((4 + g) ^ (lane & 7)) << 3)];
      acc[t] = __builtin_amdgcn_mfma_f32_16x16x32_f16(pa1, vb1, acc[t], 0, 0, 0);
    }
  }

  // epilogue: out[b][h*64+d][i] = acc / lsum   (regs r = consecutive i -> float4)
  float inv[4];
#pragma unroll
  for (int rr = 0; rr < 4; ++rr) inv[rr] = 1.f / lsum[rr];
  int ibase = ib * 64 + w * 16 + g * 4;
#pragma unroll
  for (int t = 0; t < 4; ++t) {
    int d = t * 16 + i_loc;
    float4 o4;
    o4.x = acc[t][0] * inv[0];
    o4.y = acc[t][1] * inv[1];
    o4.z = acc[t][2] * inv[2];
    o4.w = acc[t][3] * inv[3];
    *(float4*)&out[((size_t)b * Cn + h * 64 + d) * Ln + ibase] = o4;
  }
}

extern "C" void kernel_launch(void* const* d_in, const int* in_sizes, int n_in,
                              void* d_out, int out_size, void* d_ws, size_t ws_size,
                              hipStream_t stream) {
  const float* queries = (const float*)d_in[0];
  const int*   mask    = (const int*)d_in[1];
  const float* Wm      = (const float*)d_in[2];
  const float* Wq      = (const float*)d_in[3];
  float* out = (float*)d_out;
  char* ws = (char*)d_ws;
  // ws layout (32 MiB total): Xt | Qd | Kd | Vv, each 8 MiB
  f16* Xt = (f16*)(ws);
  f16* Qd = (f16*)(ws + 8388608);
  f16* Kd = (f16*)(ws + 16777216);
  f16* Vv = (f16*)(ws + 25165824);

  k_transpose<<<1024, 256, 0, stream>>>(queries, Xt);
  k_proj<<<768, 256, 0, stream>>>(Wq, Wm, Xt, Qd, Kd, Vv);
  k_attn<<<16 * 64, 256, 0, stream>>>(Qd, Kd, Vv, mask, out);
}

// Round 2
// 163.866 us; speedup vs baseline: 1.8549x; 1.8549x over previous
//
#include <hip/hip_runtime.h>

#define Bn 2
#define Cn 512
#define Ln 4096
#define Hn 8
#define Dn 64

typedef _Float16 f16;
typedef _Float16 h8 __attribute__((ext_vector_type(8)));
typedef _Float16 h4 __attribute__((ext_vector_type(4)));
typedef float f32x4 __attribute__((ext_vector_type(4)));

#define MFMA32(a, b, c) __builtin_amdgcn_mfma_f32_16x16x32_f16(a, b, c, 0, 0, 0)
#define MFMA16(a, b, c) __builtin_amdgcn_mfma_f32_16x16x16f16(a, b, c, 0, 0, 0)
#define AS1(p) ((const __attribute__((address_space(1))) void*)(p))
#define AS3(p) ((__attribute__((address_space(3))) void*)(p))

// ---------------- kernel 1: X [B][C][L] f32 -> Xt [B][L][C] f16 ----------------
__global__ __launch_bounds__(256) void k_transpose(const float* __restrict__ X,
                                                   f16* __restrict__ Xt) {
  int bid = blockIdx.x;
  int b  = bid >> 9;
  int r  = bid & 511;
  int lt = r >> 3, ct = r & 7;
  int l0 = lt << 6, c0 = ct << 6;
  __shared__ f16 t[64][66];
  int tid = threadIdx.x;
  int lx = tid & 63, cg = tid >> 6;
  const float* xb = X + ((size_t)b * Cn) * Ln;
#pragma unroll
  for (int rr = 0; rr < 16; ++rr) {
    int cl = cg * 16 + rr;
    t[lx][cl] = (f16)xb[(size_t)(c0 + cl) * Ln + l0 + lx];
  }
  __syncthreads();
  f16* xo = Xt + ((size_t)b * Ln + l0) * Cn + c0;
  int cx = tid & 63, lg = tid >> 6;
#pragma unroll
  for (int rr = 0; rr < 16; ++rr) {
    int ll = lg * 16 + rr;
    xo[(size_t)ll * Cn + cx] = t[ll][cx];
  }
}

// ---------------- kernel 2: projection GEMM (unchanged) ----------------
__global__ __launch_bounds__(256) void k_proj(const float* __restrict__ Wq,
                                              const float* __restrict__ Wm,
                                              const f16* __restrict__ Xt,
                                              f16* __restrict__ Qd,
                                              f16* __restrict__ Kd,
                                              f16* __restrict__ Vv) {
  int bid = blockIdx.x;
  int b = bid / 384;
  int r = bid % 384;
  int mt = r >> 5, nt = r & 31;
  int o0 = mt << 7, l0 = nt << 7;
  __shared__ f16 a_lds[128][40];
  __shared__ f16 b_lds[128][40];
  int tid = threadIdx.x;
  int lane = tid & 63, w = tid >> 6;
  int wr = w >> 1, wc = w & 1;
  f32x4 acc[4][4] = {};

  int sr = tid >> 1;
  int scg = (tid & 1) << 4;
  int o_s = o0 + sr;
  const float* wrow = (o_s < 512) ? (Wq + (size_t)o_s * Cn)
                                  : (Wm + (size_t)(o_s - 512) * Cn);
  const f16* xrow = Xt + ((size_t)b * Ln + l0 + sr) * Cn;

  for (int kt = 0; kt < 16; ++kt) {
    int c0 = kt << 5;
    __syncthreads();
#pragma unroll
    for (int i = 0; i < 4; ++i) {
      float4 w4 = *(const float4*)(wrow + c0 + scg + 4 * i);
      h4 hh = { (f16)w4.x, (f16)w4.y, (f16)w4.z, (f16)w4.w };
      *(h4*)&a_lds[sr][scg + 4 * i] = hh;
    }
#pragma unroll
    for (int i = 0; i < 2; ++i)
      *(h8*)&b_lds[sr][scg + 8 * i] = *(const h8*)(xrow + c0 + scg + 8 * i);
    __syncthreads();

    h8 af[4], bf[4];
#pragma unroll
    for (int mi = 0; mi < 4; ++mi)
      af[mi] = *(const h8*)&a_lds[wr * 64 + mi * 16 + (lane & 15)][(lane >> 4) * 8];
#pragma unroll
    for (int ni = 0; ni < 4; ++ni)
      bf[ni] = *(const h8*)&b_lds[wc * 64 + ni * 16 + (lane & 15)][(lane >> 4) * 8];
#pragma unroll
    for (int mi = 0; mi < 4; ++mi)
#pragma unroll
      for (int ni = 0; ni < 4; ++ni)
        acc[mi][ni] = MFMA32(af[mi], bf[ni], acc[mi][ni]);
  }

  const float QSCALE = 0.18033688011112042f;   // 2^-3 * log2(e)
  int lrow = (lane >> 4) << 2;
  int lcol = lane & 15;
#pragma unroll
  for (int mi = 0; mi < 4; ++mi) {
    int ob = o0 + wr * 64 + mi * 16 + lrow;
#pragma unroll
    for (int ni = 0; ni < 4; ++ni) {
      int lc = l0 + wc * 64 + ni * 16 + lcol;
      f32x4 a = acc[mi][ni];
      if (ob < 512) {
        int h = ob >> 6, d = ob & 63;
        h4 hh = { (f16)(a[0] * QSCALE), (f16)(a[1] * QSCALE),
                  (f16)(a[2] * QSCALE), (f16)(a[3] * QSCALE) };
        *(h4*)&Qd[(((size_t)b * Hn + h) * Ln + lc) * Dn + d] = hh;
      } else if (ob < 1024) {
        int oc = ob - 512;
        int h = oc >> 6, d = oc & 63;
        h4 hh = { (f16)a[0], (f16)a[1], (f16)a[2], (f16)a[3] };
        *(h4*)&Kd[(((size_t)b * Hn + h) * Ln + lc) * Dn + d] = hh;
      } else {
        int oc = ob - 1024;
#pragma unroll
        for (int rr = 0; rr < 4; ++rr)
          Vv[((size_t)b * Cn + oc + rr) * Ln + lc] = (f16)a[rr];
      }
    }
  }
}

// ---------------- kernel 3: flash attention, swapped-QK register-P ----------------
// grid 1024 (XCD-swizzled). Block = 4 waves; wave owns 16 q-rows; BN=64 keys/step.
// K/V double-buffered in LDS via global_load_lds (pre-swizzled source, rule 21).
__global__ __launch_bounds__(256, 4) void k_attn(const f16* __restrict__ Qd,
                                                 const f16* __restrict__ Kd,
                                                 const f16* __restrict__ Vv,
                                                 const int* __restrict__ mask,
                                                 float* __restrict__ out) {
  int bid0 = blockIdx.x;
  int bid = (bid0 & 7) * 128 + (bid0 >> 3);   // T1: 2 bh-groups per XCD
  int bh = bid >> 6, ib = bid & 63;
  int b = bh >> 3, h = bh & 7;
  int tid = threadIdx.x;
  int lane = tid & 63, w = tid >> 6;
  int il = lane & 15, g = lane >> 4;

  // [64 rows][8 chunks of 16B]; logical chunk u of row r lives at phys u^(r&7)
  __shared__ __align__(16) f16 kbuf[2][64 * 64];
  __shared__ __align__(16) f16 vbuf[2][64 * 64];

  // Q as B-fragments (col=i=il, k-chunk d = g*8.. / 32+g*8..)
  const h8* qsrc = (const h8*)(Qd + ((size_t)bh * Ln + ib * 64 + w * 16 + il) * Dn);
  h8 bq0 = qsrc[g];
  h8 bq1 = qsrc[4 + g];

  // per-64-block all-ones mask flags (one ballot, hoists mask out of hot loop)
  const int* mbase = mask + (size_t)b * Ln;
  unsigned long long flags;
  {
    const int4* mp = (const int4*)mbase + lane * 16;
    int ac = 1;
#pragma unroll
    for (int q = 0; q < 16; ++q) { int4 v = mp[q]; ac &= v.x & v.y & v.z & v.w; }
    flags = __ballot(ac == 1);
  }

  // staging: wave w covers rows w*16..w*16+15 (2 instrs of 8 rows x 128B)
  const f16* kbase = Kd + (size_t)bh * Ln * Dn;
  const f16* vbase = Vv + ((size_t)b * Cn + h * 64) * Ln;
  int koff[2], voff[2];
#pragma unroll
  for (int q = 0; q < 2; ++q) {
    int rr = w * 16 + q * 8 + (lane >> 3);
    int swz = (lane & 7) ^ (rr & 7);
    koff[q] = rr * 64 + swz * 8;          // f16 units
    voff[q] = rr * Ln + swz * 8;
  }

#define STAGE(bufi, t)                                                          \
  {                                                                             \
    _Pragma("unroll")                                                           \
    for (int q = 0; q < 2; ++q) {                                               \
      __builtin_amdgcn_global_load_lds(AS1(kbase + (size_t)(t) * 4096 + koff[q]),\
                                       AS3(&kbuf[bufi][(w * 16 + q * 8) * 64]), \
                                       16, 0, 0);                               \
      __builtin_amdgcn_global_load_lds(AS1(vbase + (size_t)(t) * 64 + voff[q]), \
                                       AS3(&vbuf[bufi][(w * 16 + q * 8) * 64]), \
                                       16, 0, 0);                               \
    }                                                                           \
  }

  f32x4 acc[4] = {};          // D[row=d=g*4+reg][col=i=il], d-tile tt
  float mrow = -1e38f;        // running max for row i=il (replicated over g)
  float lsum = 0.f;

  STAGE(0, 0);
  asm volatile("s_waitcnt vmcnt(0)" ::: "memory");
  __builtin_amdgcn_s_barrier();

  int cur = 0;
  for (int t = 0; t < 64; ++t) {
    if (t < 63) STAGE(cur ^ 1, t + 1);   // prefetch next tile into other buffer

    // ---- S^T = K·Q^T : lane holds j = T*16 + g*4 + r for its row i = il ----
    const f16* kl = kbuf[cur];
    f32x4 s[4];
#pragma unroll
    for (int T = 0; T < 4; ++T) {
      int row = (T * 16 + il) * 64;
      h8 a0 = *(const h8*)&kl[row + ((g ^ (lane & 7)) << 3)];
      h8 a1 = *(const h8*)&kl[row + (((4 + g) ^ (lane & 7)) << 3)];
      f32x4 z = {};
      z = MFMA32(a0, bq0, z);
      z = MFMA32(a1, bq1, z);
      s[T] = z;
    }

    if (!((flags >> t) & 1)) {           // rare masked path
#pragma unroll
      for (int T = 0; T < 4; ++T) {
        int4 mk = *(const int4*)(mbase + t * 64 + T * 16 + g * 4);
        s[T][0] = mk.x ? s[T][0] : -3.0e4f;
        s[T][1] = mk.y ? s[T][1] : -3.0e4f;
        s[T][2] = mk.z ? s[T][2] : -3.0e4f;
        s[T][3] = mk.w ? s[T][3] : -3.0e4f;
      }
    }

    // ---- online softmax: in-lane over 16 + 2 shuffles ----
    float mx;
    {
      float a = fmaxf(fmaxf(s[0][0], s[0][1]), fmaxf(s[0][2], s[0][3]));
      float b2 = fmaxf(fmaxf(s[1][0], s[1][1]), fmaxf(s[1][2], s[1][3]));
      float c = fmaxf(fmaxf(s[2][0], s[2][1]), fmaxf(s[2][2], s[2][3]));
      float d = fmaxf(fmaxf(s[3][0], s[3][1]), fmaxf(s[3][2], s[3][3]));
      mx = fmaxf(fmaxf(a, b2), fmaxf(c, d));
    }
    mx = fmaxf(mx, __shfl_xor(mx, 16));
    mx = fmaxf(mx, __shfl_xor(mx, 32));

    if (__any(mx > mrow + 8.f)) {        // T13 defer-max, THR=8 (p <= 2^8, f16-safe)
      float mn = fmaxf(mrow, mx);
      float al = __builtin_amdgcn_exp2f(mrow - mn);
      lsum *= al;
#pragma unroll
      for (int tt = 0; tt < 4; ++tt) {
        f32x4 a = acc[tt];
        a[0] *= al; a[1] *= al; a[2] *= al; a[3] *= al;
        acc[tt] = a;
      }
      mrow = mn;
    }

    h4 pa[4];
    float rs = 0.f;
#pragma unroll
    for (int T = 0; T < 4; ++T) {
      float p0 = __builtin_amdgcn_exp2f(s[T][0] - mrow);
      float p1 = __builtin_amdgcn_exp2f(s[T][1] - mrow);
      float p2 = __builtin_amdgcn_exp2f(s[T][2] - mrow);
      float p3 = __builtin_amdgcn_exp2f(s[T][3] - mrow);
      h4 hh = { (f16)p0, (f16)p1, (f16)p2, (f16)p3 };
      pa[T] = hh;
      rs += (p0 + p1) + (p2 + p3);
    }
    rs += __shfl_xor(rs, 16);
    rs += __shfl_xor(rs, 32);
    lsum += rs;

    // ---- O^T += V^T·P^T : A = V-frag (row=d, k=j), B = P regs (col=i, k=j) ----
    const f16* vl = vbuf[cur];
#pragma unroll
    for (int tt = 0; tt < 4; ++tt) {
      int drow = tt * 16 + il;
#pragma unroll
      for (int T = 0; T < 4; ++T) {
        int chunk = T * 2 + (g >> 1);
        h4 va = *(const h4*)&vl[drow * 64 + ((chunk ^ (drow & 7)) << 3) + ((g & 1) << 2)];
        acc[tt] = MFMA16(va, pa[T], acc[tt]);
      }
    }

    asm volatile("s_waitcnt vmcnt(0)" ::: "memory");  // next tile landed
    __builtin_amdgcn_s_barrier();                      // everyone done with cur
    cur ^= 1;
  }

  // ---- epilogue: out[b][h*64+d][i], d = tt*16 + g*4 + r, i = ib*64 + w*16 + il ----
  float inv = 1.f / lsum;
  size_t obase = ((size_t)b * Cn + h * 64) * Ln + ib * 64 + w * 16 + il;
#pragma unroll
  for (int tt = 0; tt < 4; ++tt)
#pragma unroll
    for (int rr = 0; rr < 4; ++rr) {
      int d = tt * 16 + g * 4 + rr;
      out[obase + (size_t)d * Ln] = acc[tt][rr] * inv;
    }
}

extern "C" void kernel_launch(void* const* d_in, const int* in_sizes, int n_in,
                              void* d_out, int out_size, void* d_ws, size_t ws_size,
                              hipStream_t stream) {
  const float* queries = (const float*)d_in[0];
  const int*   mask    = (const int*)d_in[1];
  const float* Wm      = (const float*)d_in[2];
  const float* Wq      = (const float*)d_in[3];
  float* out = (float*)d_out;
  char* ws = (char*)d_ws;
  f16* Xt = (f16*)(ws);
  f16* Qd = (f16*)(ws + 8388608);
  f16* Kd = (f16*)(ws + 16777216);
  f16* Vv = (f16*)(ws + 25165824);

  k_transpose<<<1024, 256, 0, stream>>>(queries, Xt);
  k_proj<<<768, 256, 0, stream>>>(Wq, Wm, Xt, Qd, Kd, Vv);
  k_attn<<<16 * 64, 256, 0, stream>>>(Qd, Kd, Vv, mask, out);
}

// Round 3
// 158.445 us; speedup vs baseline: 1.9183x; 1.0342x over previous
//
#include <hip/hip_runtime.h>

#define Bn 2
#define Cn 512
#define Ln 4096
#define Hn 8
#define Dn 64

typedef _Float16 f16;
typedef _Float16 h8 __attribute__((ext_vector_type(8)));
typedef _Float16 h4 __attribute__((ext_vector_type(4)));
typedef float f32x4 __attribute__((ext_vector_type(4)));

#define MFMA32(a, b, c) __builtin_amdgcn_mfma_f32_16x16x32_f16(a, b, c, 0, 0, 0)
#define MFMA16(a, b, c) __builtin_amdgcn_mfma_f32_16x16x16f16(a, b, c, 0, 0, 0)
#define AS1(p) ((const __attribute__((address_space(1))) void*)(p))
#define AS3(p) ((__attribute__((address_space(3))) void*)(p))

// ---------------- kernel 1: X [B][C][L] f32 -> Xt [B][L][C] f16 ----------------
__global__ __launch_bounds__(256) void k_transpose(const float* __restrict__ X,
                                                   f16* __restrict__ Xt) {
  int bid = blockIdx.x;
  int b  = bid >> 9;
  int r  = bid & 511;
  int lt = r >> 3, ct = r & 7;
  int l0 = lt << 6, c0 = ct << 6;
  __shared__ f16 t[64][66];
  int tid = threadIdx.x;
  int lx = tid & 63, cg = tid >> 6;
  const float* xb = X + ((size_t)b * Cn) * Ln;
#pragma unroll
  for (int rr = 0; rr < 16; ++rr) {
    int cl = cg * 16 + rr;
    t[lx][cl] = (f16)xb[(size_t)(c0 + cl) * Ln + l0 + lx];
  }
  __syncthreads();
  f16* xo = Xt + ((size_t)b * Ln + l0) * Cn + c0;
  int cx = tid & 63, lg = tid >> 6;
#pragma unroll
  for (int rr = 0; rr < 16; ++rr) {
    int ll = lg * 16 + rr;
    xo[(size_t)ll * Cn + cx] = t[ll][cx];
  }
}

// ---------------- kernel 2: projection GEMM (unchanged) ----------------
__global__ __launch_bounds__(256) void k_proj(const float* __restrict__ Wq,
                                              const float* __restrict__ Wm,
                                              const f16* __restrict__ Xt,
                                              f16* __restrict__ Qd,
                                              f16* __restrict__ Kd,
                                              f16* __restrict__ Vv) {
  int bid = blockIdx.x;
  int b = bid / 384;
  int r = bid % 384;
  int mt = r >> 5, nt = r & 31;
  int o0 = mt << 7, l0 = nt << 7;
  __shared__ f16 a_lds[128][40];
  __shared__ f16 b_lds[128][40];
  int tid = threadIdx.x;
  int lane = tid & 63, w = tid >> 6;
  int wr = w >> 1, wc = w & 1;
  f32x4 acc[4][4] = {};

  int sr = tid >> 1;
  int scg = (tid & 1) << 4;
  int o_s = o0 + sr;
  const float* wrow = (o_s < 512) ? (Wq + (size_t)o_s * Cn)
                                  : (Wm + (size_t)(o_s - 512) * Cn);
  const f16* xrow = Xt + ((size_t)b * Ln + l0 + sr) * Cn;

  for (int kt = 0; kt < 16; ++kt) {
    int c0 = kt << 5;
    __syncthreads();
#pragma unroll
    for (int i = 0; i < 4; ++i) {
      float4 w4 = *(const float4*)(wrow + c0 + scg + 4 * i);
      h4 hh = { (f16)w4.x, (f16)w4.y, (f16)w4.z, (f16)w4.w };
      *(h4*)&a_lds[sr][scg + 4 * i] = hh;
    }
#pragma unroll
    for (int i = 0; i < 2; ++i)
      *(h8*)&b_lds[sr][scg + 8 * i] = *(const h8*)(xrow + c0 + scg + 8 * i);
    __syncthreads();

    h8 af[4], bf[4];
#pragma unroll
    for (int mi = 0; mi < 4; ++mi)
      af[mi] = *(const h8*)&a_lds[wr * 64 + mi * 16 + (lane & 15)][(lane >> 4) * 8];
#pragma unroll
    for (int ni = 0; ni < 4; ++ni)
      bf[ni] = *(const h8*)&b_lds[wc * 64 + ni * 16 + (lane & 15)][(lane >> 4) * 8];
#pragma unroll
    for (int mi = 0; mi < 4; ++mi)
#pragma unroll
      for (int ni = 0; ni < 4; ++ni)
        acc[mi][ni] = MFMA32(af[mi], bf[ni], acc[mi][ni]);
  }

  const float QSCALE = 0.18033688011112042f;   // 2^-3 * log2(e)
  int lrow = (lane >> 4) << 2;
  int lcol = lane & 15;
#pragma unroll
  for (int mi = 0; mi < 4; ++mi) {
    int ob = o0 + wr * 64 + mi * 16 + lrow;
#pragma unroll
    for (int ni = 0; ni < 4; ++ni) {
      int lc = l0 + wc * 64 + ni * 16 + lcol;
      f32x4 a = acc[mi][ni];
      if (ob < 512) {
        int h = ob >> 6, d = ob & 63;
        h4 hh = { (f16)(a[0] * QSCALE), (f16)(a[1] * QSCALE),
                  (f16)(a[2] * QSCALE), (f16)(a[3] * QSCALE) };
        *(h4*)&Qd[(((size_t)b * Hn + h) * Ln + lc) * Dn + d] = hh;
      } else if (ob < 1024) {
        int oc = ob - 512;
        int h = oc >> 6, d = oc & 63;
        h4 hh = { (f16)a[0], (f16)a[1], (f16)a[2], (f16)a[3] };
        *(h4*)&Kd[(((size_t)b * Hn + h) * Ln + lc) * Dn + d] = hh;
      } else {
        int oc = ob - 1024;
#pragma unroll
        for (int rr = 0; rr < 4; ++rr)
          Vv[((size_t)b * Cn + oc + rr) * Ln + lc] = (f16)a[rr];
      }
    }
  }
}

// ---------------- kernel 3: flash attention, 32 q-rows/wave ----------------
// grid 512 (XCD-swizzled): 16 bh x 32 i-blocks of 128 q. Block = 4 waves.
// Wave owns 32 q (two MFMA col-sets A/B); K/V LDS reads shared across sets.
__global__ __launch_bounds__(256, 2) void k_attn(const f16* __restrict__ Qd,
                                                 const f16* __restrict__ Kd,
                                                 const f16* __restrict__ Vv,
                                                 const int* __restrict__ mask,
                                                 float* __restrict__ out) {
  int bid0 = blockIdx.x;
  int bid = (bid0 & 7) * 64 + (bid0 >> 3);   // T1: 64 blocks (2 bh) per XCD
  int bh = bid >> 5, ib = bid & 31;
  int b = bh >> 3, h = bh & 7;
  int tid = threadIdx.x;
  int lane = tid & 63, w = tid >> 6;
  int il = lane & 15, g = lane >> 4;

  // [64 rows][8 chunks of 16B]; logical chunk u of row r lives at phys u^(r&7)
  __shared__ __align__(16) f16 kbuf[2][64 * 64];
  __shared__ __align__(16) f16 vbuf[2][64 * 64];

  int qb = ib * 128 + w * 32;
  const h8* qsA = (const h8*)(Qd + ((size_t)bh * Ln + qb + il) * Dn);
  const h8* qsB = (const h8*)(Qd + ((size_t)bh * Ln + qb + 16 + il) * Dn);
  h8 bqA0 = qsA[g], bqA1 = qsA[4 + g];
  h8 bqB0 = qsB[g], bqB1 = qsB[4 + g];

  // per-64-block all-ones mask flags
  const int* mbase = mask + (size_t)b * Ln;
  unsigned long long flags;
  {
    const int4* mp = (const int4*)mbase + lane * 16;
    int ac = 1;
#pragma unroll
    for (int q = 0; q < 16; ++q) { int4 v = mp[q]; ac &= v.x & v.y & v.z & v.w; }
    flags = __ballot(ac == 1);
  }

  const f16* kbase = Kd + (size_t)bh * Ln * Dn;
  const f16* vbase = Vv + ((size_t)b * Cn + h * 64) * Ln;
  int koff[2], voff[2];
#pragma unroll
  for (int q = 0; q < 2; ++q) {
    int rr = w * 16 + q * 8 + (lane >> 3);
    int swz = (lane & 7) ^ (rr & 7);
    koff[q] = rr * 64 + swz * 8;
    voff[q] = rr * Ln + swz * 8;
  }

#define STAGE(bufi, t)                                                          \
  {                                                                             \
    _Pragma("unroll")                                                           \
    for (int q = 0; q < 2; ++q) {                                               \
      __builtin_amdgcn_global_load_lds(AS1(kbase + (size_t)(t) * 4096 + koff[q]),\
                                       AS3(&kbuf[bufi][(w * 16 + q * 8) * 64]), \
                                       16, 0, 0);                               \
      __builtin_amdgcn_global_load_lds(AS1(vbase + (size_t)(t) * 64 + voff[q]), \
                                       AS3(&vbuf[bufi][(w * 16 + q * 8) * 64]), \
                                       16, 0, 0);                               \
    }                                                                           \
  }

  f32x4 accA[4] = {}, accB[4] = {};
  float mA = -1e38f, mB = -1e38f;
  float lA = 0.f, lB = 0.f;

  STAGE(0, 0);
  asm volatile("s_waitcnt vmcnt(0)" ::: "memory");
  __builtin_amdgcn_s_barrier();

  int cur = 0;
  for (int t = 0; t < 64; ++t) {
    if (t < 63) STAGE(cur ^ 1, t + 1);

    // ---- S^T = K·Q^T for both q-sets; K-frags shared ----
    const f16* kl = kbuf[cur];
    f32x4 sA[4], sB[4];
#pragma unroll
    for (int T = 0; T < 4; ++T) {
      int row = (T * 16 + il) * 64;
      h8 a0 = *(const h8*)&kl[row + ((g ^ (il & 7)) << 3)];
      h8 a1 = *(const h8*)&kl[row + (((4 + g) ^ (il & 7)) << 3)];
      f32x4 zA = {}, zB = {};
      zA = MFMA32(a0, bqA0, zA);
      zA = MFMA32(a1, bqA1, zA);
      zB = MFMA32(a0, bqB0, zB);
      zB = MFMA32(a1, bqB1, zB);
      sA[T] = zA; sB[T] = zB;
    }

    if (!((flags >> t) & 1)) {
#pragma unroll
      for (int T = 0; T < 4; ++T) {
        int4 mk = *(const int4*)(mbase + t * 64 + T * 16 + g * 4);
        sA[T][0] = mk.x ? sA[T][0] : -3.0e4f;
        sA[T][1] = mk.y ? sA[T][1] : -3.0e4f;
        sA[T][2] = mk.z ? sA[T][2] : -3.0e4f;
        sA[T][3] = mk.w ? sA[T][3] : -3.0e4f;
        sB[T][0] = mk.x ? sB[T][0] : -3.0e4f;
        sB[T][1] = mk.y ? sB[T][1] : -3.0e4f;
        sB[T][2] = mk.z ? sB[T][2] : -3.0e4f;
        sB[T][3] = mk.w ? sB[T][3] : -3.0e4f;
      }
    }

    // ---- online softmax, set A ----
    h4 paA[4], paB[4];
    {
      float a = fmaxf(fmaxf(sA[0][0], sA[0][1]), fmaxf(sA[0][2], sA[0][3]));
      float b2 = fmaxf(fmaxf(sA[1][0], sA[1][1]), fmaxf(sA[1][2], sA[1][3]));
      float c = fmaxf(fmaxf(sA[2][0], sA[2][1]), fmaxf(sA[2][2], sA[2][3]));
      float d = fmaxf(fmaxf(sA[3][0], sA[3][1]), fmaxf(sA[3][2], sA[3][3]));
      float mx = fmaxf(fmaxf(a, b2), fmaxf(c, d));
      mx = fmaxf(mx, __shfl_xor(mx, 16));
      mx = fmaxf(mx, __shfl_xor(mx, 32));
      if (__any(mx > mA + 8.f)) {
        float mn = fmaxf(mA, mx);
        float al = __builtin_amdgcn_exp2f(mA - mn);
        lA *= al;
#pragma unroll
        for (int tt = 0; tt < 4; ++tt) {
          f32x4 a4 = accA[tt];
          a4[0] *= al; a4[1] *= al; a4[2] *= al; a4[3] *= al;
          accA[tt] = a4;
        }
        mA = mn;
      }
      float rs = 0.f;
#pragma unroll
      for (int T = 0; T < 4; ++T) {
        float p0 = __builtin_amdgcn_exp2f(sA[T][0] - mA);
        float p1 = __builtin_amdgcn_exp2f(sA[T][1] - mA);
        float p2 = __builtin_amdgcn_exp2f(sA[T][2] - mA);
        float p3 = __builtin_amdgcn_exp2f(sA[T][3] - mA);
        h4 hh = { (f16)p0, (f16)p1, (f16)p2, (f16)p3 };
        paA[T] = hh;
        rs += (p0 + p1) + (p2 + p3);
      }
      rs += __shfl_xor(rs, 16);
      rs += __shfl_xor(rs, 32);
      lA += rs;
    }
    // ---- online softmax, set B ----
    {
      float a = fmaxf(fmaxf(sB[0][0], sB[0][1]), fmaxf(sB[0][2], sB[0][3]));
      float b2 = fmaxf(fmaxf(sB[1][0], sB[1][1]), fmaxf(sB[1][2], sB[1][3]));
      float c = fmaxf(fmaxf(sB[2][0], sB[2][1]), fmaxf(sB[2][2], sB[2][3]));
      float d = fmaxf(fmaxf(sB[3][0], sB[3][1]), fmaxf(sB[3][2], sB[3][3]));
      float mx = fmaxf(fmaxf(a, b2), fmaxf(c, d));
      mx = fmaxf(mx, __shfl_xor(mx, 16));
      mx = fmaxf(mx, __shfl_xor(mx, 32));
      if (__any(mx > mB + 8.f)) {
        float mn = fmaxf(mB, mx);
        float al = __builtin_amdgcn_exp2f(mB - mn);
        lB *= al;
#pragma unroll
        for (int tt = 0; tt < 4; ++tt) {
          f32x4 a4 = accB[tt];
          a4[0] *= al; a4[1] *= al; a4[2] *= al; a4[3] *= al;
          accB[tt] = a4;
        }
        mB = mn;
      }
      float rs = 0.f;
#pragma unroll
      for (int T = 0; T < 4; ++T) {
        float p0 = __builtin_amdgcn_exp2f(sB[T][0] - mB);
        float p1 = __builtin_amdgcn_exp2f(sB[T][1] - mB);
        float p2 = __builtin_amdgcn_exp2f(sB[T][2] - mB);
        float p3 = __builtin_amdgcn_exp2f(sB[T][3] - mB);
        h4 hh = { (f16)p0, (f16)p1, (f16)p2, (f16)p3 };
        paB[T] = hh;
        rs += (p0 + p1) + (p2 + p3);
      }
      rs += __shfl_xor(rs, 16);
      rs += __shfl_xor(rs, 32);
      lB += rs;
    }

    // ---- O^T += V^T·P^T for both sets; V-frags shared ----
    const f16* vl = vbuf[cur];
#pragma unroll
    for (int tt = 0; tt < 4; ++tt) {
      int drow = tt * 16 + il;
#pragma unroll
      for (int T = 0; T < 4; ++T) {
        int chunk = T * 2 + (g >> 1);
        h4 va = *(const h4*)&vl[drow * 64 + ((chunk ^ (drow & 7)) << 3) + ((g & 1) << 2)];
        accA[tt] = MFMA16(va, paA[T], accA[tt]);
        accB[tt] = MFMA16(va, paB[T], accB[tt]);
      }
    }

    asm volatile("s_waitcnt vmcnt(0)" ::: "memory");
    __builtin_amdgcn_s_barrier();
    cur ^= 1;
  }

  // ---- epilogue ----
  float invA = 1.f / lA, invB = 1.f / lB;
  size_t obA = ((size_t)b * Cn + h * 64) * Ln + qb + il;
  size_t obB = obA + 16;
#pragma unroll
  for (int tt = 0; tt < 4; ++tt)
#pragma unroll
    for (int rr = 0; rr < 4; ++rr) {
      int d = tt * 16 + g * 4 + rr;
      out[obA + (size_t)d * Ln] = accA[tt][rr] * invA;
      out[obB + (size_t)d * Ln] = accB[tt][rr] * invB;
    }
}

extern "C" void kernel_launch(void* const* d_in, const int* in_sizes, int n_in,
                              void* d_out, int out_size, void* d_ws, size_t ws_size,
                              hipStream_t stream) {
  const float* queries = (const float*)d_in[0];
  const int*   mask    = (const int*)d_in[1];
  const float* Wm      = (const float*)d_in[2];
  const float* Wq      = (const float*)d_in[3];
  float* out = (float*)d_out;
  char* ws = (char*)d_ws;
  f16* Xt = (f16*)(ws);
  f16* Qd = (f16*)(ws + 8388608);
  f16* Kd = (f16*)(ws + 16777216);
  f16* Vv = (f16*)(ws + 25165824);

  k_transpose<<<1024, 256, 0, stream>>>(queries, Xt);
  k_proj<<<768, 256, 0, stream>>>(Wq, Wm, Xt, Qd, Kd, Vv);
  k_attn<<<512, 256, 0, stream>>>(Qd, Kd, Vv, mask, out);
}

// Round 4
// 145.897 us; speedup vs baseline: 2.0833x; 1.0860x over previous
//
#include <hip/hip_runtime.h>

#define Bn 2
#define Cn 512
#define Ln 4096
#define Hn 8
#define Dn 64

typedef _Float16 f16;
typedef _Float16 h8 __attribute__((ext_vector_type(8)));
typedef _Float16 h4 __attribute__((ext_vector_type(4)));
typedef _Float16 h2 __attribute__((ext_vector_type(2)));
typedef float f32x4 __attribute__((ext_vector_type(4)));
typedef float f32x16 __attribute__((ext_vector_type(16)));

#define MFMA32(a, b, c) __builtin_amdgcn_mfma_f32_16x16x32_f16(a, b, c, 0, 0, 0)
#define MFMA3216(a, b, c) __builtin_amdgcn_mfma_f32_32x32x16_f16(a, b, c, 0, 0, 0)
#define AS1(p) ((const __attribute__((address_space(1))) void*)(p))
#define AS3(p) ((__attribute__((address_space(3))) void*)(p))

// ---------------- kernel 1: X [B][C][L] f32 -> Xt [B][L][C] f16 ----------------
__global__ __launch_bounds__(256) void k_transpose(const float* __restrict__ X,
                                                   f16* __restrict__ Xt) {
  int bid = blockIdx.x;
  int b  = bid >> 9;
  int r  = bid & 511;
  int lt = r >> 3, ct = r & 7;
  int l0 = lt << 6, c0 = ct << 6;
  __shared__ f16 t[64][66];
  int tid = threadIdx.x;
  int lx = tid & 63, cg = tid >> 6;
  const float* xb = X + ((size_t)b * Cn) * Ln;
#pragma unroll
  for (int rr = 0; rr < 16; ++rr) {
    int cl = cg * 16 + rr;
    t[lx][cl] = (f16)xb[(size_t)(c0 + cl) * Ln + l0 + lx];
  }
  __syncthreads();
  f16* xo = Xt + ((size_t)b * Ln + l0) * Cn + c0;
  int cx = tid & 63, lg = tid >> 6;
#pragma unroll
  for (int rr = 0; rr < 16; ++rr) {
    int ll = lg * 16 + rr;
    xo[(size_t)ll * Cn + cx] = t[ll][cx];
  }
}

// ---------------- kernel 2: projection GEMM (unchanged) ----------------
__global__ __launch_bounds__(256) void k_proj(const float* __restrict__ Wq,
                                              const float* __restrict__ Wm,
                                              const f16* __restrict__ Xt,
                                              f16* __restrict__ Qd,
                                              f16* __restrict__ Kd,
                                              f16* __restrict__ Vv) {
  int bid = blockIdx.x;
  int b = bid / 384;
  int r = bid % 384;
  int mt = r >> 5, nt = r & 31;
  int o0 = mt << 7, l0 = nt << 7;
  __shared__ f16 a_lds[128][40];
  __shared__ f16 b_lds[128][40];
  int tid = threadIdx.x;
  int lane = tid & 63, w = tid >> 6;
  int wr = w >> 1, wc = w & 1;
  f32x4 acc[4][4] = {};

  int sr = tid >> 1;
  int scg = (tid & 1) << 4;
  int o_s = o0 + sr;
  const float* wrow = (o_s < 512) ? (Wq + (size_t)o_s * Cn)
                                  : (Wm + (size_t)(o_s - 512) * Cn);
  const f16* xrow = Xt + ((size_t)b * Ln + l0 + sr) * Cn;

  for (int kt = 0; kt < 16; ++kt) {
    int c0 = kt << 5;
    __syncthreads();
#pragma unroll
    for (int i = 0; i < 4; ++i) {
      float4 w4 = *(const float4*)(wrow + c0 + scg + 4 * i);
      h4 hh = { (f16)w4.x, (f16)w4.y, (f16)w4.z, (f16)w4.w };
      *(h4*)&a_lds[sr][scg + 4 * i] = hh;
    }
#pragma unroll
    for (int i = 0; i < 2; ++i)
      *(h8*)&b_lds[sr][scg + 8 * i] = *(const h8*)(xrow + c0 + scg + 8 * i);
    __syncthreads();

    h8 af[4], bf[4];
#pragma unroll
    for (int mi = 0; mi < 4; ++mi)
      af[mi] = *(const h8*)&a_lds[wr * 64 + mi * 16 + (lane & 15)][(lane >> 4) * 8];
#pragma unroll
    for (int ni = 0; ni < 4; ++ni)
      bf[ni] = *(const h8*)&b_lds[wc * 64 + ni * 16 + (lane & 15)][(lane >> 4) * 8];
#pragma unroll
    for (int mi = 0; mi < 4; ++mi)
#pragma unroll
      for (int ni = 0; ni < 4; ++ni)
        acc[mi][ni] = MFMA32(af[mi], bf[ni], acc[mi][ni]);
  }

  const float QSCALE = 0.18033688011112042f;   // 2^-3 * log2(e)
  int lrow = (lane >> 4) << 2;
  int lcol = lane & 15;
#pragma unroll
  for (int mi = 0; mi < 4; ++mi) {
    int ob = o0 + wr * 64 + mi * 16 + lrow;
#pragma unroll
    for (int ni = 0; ni < 4; ++ni) {
      int lc = l0 + wc * 64 + ni * 16 + lcol;
      f32x4 a = acc[mi][ni];
      if (ob < 512) {
        int h = ob >> 6, d = ob & 63;
        h4 hh = { (f16)(a[0] * QSCALE), (f16)(a[1] * QSCALE),
                  (f16)(a[2] * QSCALE), (f16)(a[3] * QSCALE) };
        *(h4*)&Qd[(((size_t)b * Hn + h) * Ln + lc) * Dn + d] = hh;
      } else if (ob < 1024) {
        int oc = ob - 512;
        int h = oc >> 6, d = oc & 63;
        h4 hh = { (f16)a[0], (f16)a[1], (f16)a[2], (f16)a[3] };
        *(h4*)&Kd[(((size_t)b * Hn + h) * Ln + lc) * Dn + d] = hh;
      } else {
        int oc = ob - 1024;
#pragma unroll
        for (int rr = 0; rr < 4; ++rr)
          Vv[((size_t)b * Cn + oc + rr) * Ln + lc] = (f16)a[rr];
      }
    }
  }
}

// ---------------- kernel 3: flash attention, 32x32x16 MFMA ----------------
// grid 512 (XCD-swizzled): 16 bh x 32 i-blocks of 128 q. Block = 4 waves x 32 q.
// Wave-iter: QK = 8 mfma_32x32x16, PV = 8 mfma_32x32x16; lane owns one q-row.
__global__ __launch_bounds__(256, 2) void k_attn(const f16* __restrict__ Qd,
                                                 const f16* __restrict__ Kd,
                                                 const f16* __restrict__ Vv,
                                                 const int* __restrict__ mask,
                                                 float* __restrict__ out) {
  int bid0 = blockIdx.x;
  int bid = (bid0 & 7) * 64 + (bid0 >> 3);   // T1: 64 blocks (2 bh) per XCD
  int bh = bid >> 5, ib = bid & 31;
  int b = bh >> 3, h = bh & 7;
  int tid = threadIdx.x;
  int lane = tid & 63, w = tid >> 6;
  int il = lane & 31, hi = lane >> 5;

  // [64 rows][8 chunks of 16B]; logical chunk u of row r lives at phys u^(r&7)
  __shared__ __align__(16) f16 kbuf[2][64 * 64];
  __shared__ __align__(16) f16 vbuf[2][64 * 64];

  int qb = ib * 128 + w * 32;
  // Q B-frag: col=i=il, k(d) = dt*16 + hi*8 + e
  const f16* qp = Qd + ((size_t)bh * Ln + qb + il) * Dn;
  h8 qreg[4];
#pragma unroll
  for (int dt = 0; dt < 4; ++dt)
    qreg[dt] = *(const h8*)(qp + dt * 16 + hi * 8);

  // per-64-block all-ones mask flags
  const int* mbase = mask + (size_t)b * Ln;
  unsigned long long flags;
  {
    const int4* mp = (const int4*)mbase + lane * 16;
    int ac = 1;
#pragma unroll
    for (int q = 0; q < 16; ++q) { int4 v = mp[q]; ac &= v.x & v.y & v.z & v.w; }
    flags = __ballot(ac == 1);
  }

  const f16* kbase = Kd + (size_t)bh * Ln * Dn;
  const f16* vbase = Vv + ((size_t)b * Cn + h * 64) * Ln;
  int koff[2], voff[2];
#pragma unroll
  for (int q = 0; q < 2; ++q) {
    int rr = w * 16 + q * 8 + (lane >> 3);
    int swz = (lane & 7) ^ (rr & 7);
    koff[q] = rr * 64 + swz * 8;
    voff[q] = rr * Ln + swz * 8;
  }

#define STAGE(bufi, t)                                                          \
  {                                                                             \
    _Pragma("unroll")                                                           \
    for (int q = 0; q < 2; ++q) {                                               \
      __builtin_amdgcn_global_load_lds(AS1(kbase + (size_t)(t) * 4096 + koff[q]),\
                                       AS3(&kbuf[bufi][(w * 16 + q * 8) * 64]), \
                                       16, 0, 0);                               \
      __builtin_amdgcn_global_load_lds(AS1(vbase + (size_t)(t) * 64 + voff[q]), \
                                       AS3(&vbuf[bufi][(w * 16 + q * 8) * 64]), \
                                       16, 0, 0);                               \
    }                                                                           \
  }

  f32x16 acc[2] = {};       // O^T: col=i=il, row d = dt*32 + (r&3)+8*(r>>2)+4*hi
  float mrow = -1e38f;      // running max for q-row i (replicated over hi)
  float lsum = 0.f;

  STAGE(0, 0);
  asm volatile("s_waitcnt vmcnt(0)" ::: "memory");
  __builtin_amdgcn_s_barrier();

  int swz7 = il & 7;
  int cur = 0;
  for (int t = 0; t < 64; ++t) {
    if (t < 63) STAGE(cur ^ 1, t + 1);

    // ---- S^T = K·Q^T : lane holds q-row i=il, j = jt*32 + (r&3)+8*(r>>2)+4*hi ----
    const f16* kl = kbuf[cur];
    f32x16 s0 = {}, s1 = {};
    __builtin_amdgcn_s_setprio(1);
#pragma unroll
    for (int dt = 0; dt < 4; ++dt) {
      int c = ((dt * 2 + hi) ^ swz7) << 3;
      h8 ak0 = *(const h8*)&kl[il * 64 + c];
      h8 ak1 = *(const h8*)&kl[(32 + il) * 64 + c];
      s0 = MFMA3216(ak0, qreg[dt], s0);
      s1 = MFMA3216(ak1, qreg[dt], s1);
    }
    __builtin_amdgcn_s_setprio(0);

    if (!((flags >> t) & 1)) {          // rare masked path
#pragma unroll
      for (int r = 0; r < 16; ++r) {
        int j = t * 64 + (r & 3) + 8 * (r >> 2) + 4 * hi;
        if (!mbase[j])      s0[r] = -3.0e4f;
        if (!mbase[j + 32]) s1[r] = -3.0e4f;
      }
    }

    // ---- online softmax: in-lane tree + one cross-half shuffle ----
    float mx;
    {
      float m0 = fmaxf(s0[0], s0[1]), m1 = fmaxf(s0[2], s0[3]);
      float m2 = fmaxf(s0[4], s0[5]), m3 = fmaxf(s0[6], s0[7]);
      float m4 = fmaxf(s0[8], s0[9]), m5 = fmaxf(s0[10], s0[11]);
      float m6 = fmaxf(s0[12], s0[13]), m7 = fmaxf(s0[14], s0[15]);
      float n0 = fmaxf(s1[0], s1[1]), n1 = fmaxf(s1[2], s1[3]);
      float n2 = fmaxf(s1[4], s1[5]), n3 = fmaxf(s1[6], s1[7]);
      float n4 = fmaxf(s1[8], s1[9]), n5 = fmaxf(s1[10], s1[11]);
      float n6 = fmaxf(s1[12], s1[13]), n7 = fmaxf(s1[14], s1[15]);
      float a = fmaxf(fmaxf(m0, m1), fmaxf(m2, m3));
      float b2 = fmaxf(fmaxf(m4, m5), fmaxf(m6, m7));
      float c = fmaxf(fmaxf(n0, n1), fmaxf(n2, n3));
      float d = fmaxf(fmaxf(n4, n5), fmaxf(n6, n7));
      mx = fmaxf(fmaxf(a, b2), fmaxf(c, d));
    }
    mx = fmaxf(mx, __shfl_xor(mx, 32));

    if (__any(mx > mrow + 8.f)) {       // T13 defer-max, THR=8 (P <= 2^8, f16-safe)
      float mn = fmaxf(mrow, mx);
      float al = __builtin_amdgcn_exp2f(mrow - mn);
      lsum *= al;
#pragma unroll
      for (int r = 0; r < 16; ++r) { acc[0][r] *= al; acc[1][r] *= al; }
      mrow = mn;
    }

#pragma unroll
    for (int r = 0; r < 16; ++r) {
      s0[r] = __builtin_amdgcn_exp2f(s0[r] - mrow);
      s1[r] = __builtin_amdgcn_exp2f(s1[r] - mrow);
    }

    float rs = 0.f;
#pragma unroll
    for (int r = 0; r < 16; r += 4) {
      rs += ((s0[r] + s0[r + 1]) + (s0[r + 2] + s0[r + 3]));
      rs += ((s1[r] + s1[r + 1]) + (s1[r + 2] + s1[r + 3]));
    }
    rs += __shfl_xor(rs, 32);
    lsum += rs;

    // ---- P pack to f16 pairs: d[jt][a*2+c] = (p[j], p[j+1]), j = 8a+4hi+2c ----
    float dw0[8], dw1[8];
#pragma unroll
    for (int r = 0; r < 16; r += 2) {
      dw0[r >> 1] = __builtin_bit_cast(float, __builtin_amdgcn_cvt_pkrtz(s0[r], s0[r + 1]));
      dw1[r >> 1] = __builtin_bit_cast(float, __builtin_amdgcn_cvt_pkrtz(s1[r], s1[r + 1]));
    }

    // ---- build PV B-frags: pb[jt16] holds P[j = jt16*16 + hi*8 + e][i] ----
    h8 pb[4];
#pragma unroll
    for (int jt = 0; jt < 4; ++jt) {
      const float* dd = (jt < 2) ? dw0 : dw1;
      int base = (jt & 1) * 4;
      float x0 = dd[base + 0], x1 = dd[base + 1];
      float y0 = dd[base + 2], y1 = dd[base + 3];
      float v0 = hi ? x0 : y0, v1 = hi ? x1 : y1;   // what the other half needs
      float p0 = __shfl_xor(v0, 32), p1 = __shfl_xor(v1, 32);
      union { h8 v; float f[4]; } u;
      u.f[0] = hi ? p0 : x0;
      u.f[1] = hi ? p1 : x1;
      u.f[2] = hi ? y0 : p0;
      u.f[3] = hi ? y1 : p1;
      pb[jt] = u.v;
    }

    // ---- O^T += V^T·P^T : A = V-frag (row=d, k=j), B = pb ----
    const f16* vl = vbuf[cur];
    __builtin_amdgcn_s_setprio(1);
#pragma unroll
    for (int dt = 0; dt < 2; ++dt) {
      int rv = dt * 32 + il;
#pragma unroll
      for (int jt = 0; jt < 4; ++jt) {
        h8 av = *(const h8*)&vl[rv * 64 + (((jt * 2 + hi) ^ swz7) << 3)];
        acc[dt] = MFMA3216(av, pb[jt], acc[dt]);
      }
    }
    __builtin_amdgcn_s_setprio(0);

    asm volatile("s_waitcnt vmcnt(0)" ::: "memory");
    __builtin_amdgcn_s_barrier();
    cur ^= 1;
  }

  // ---- epilogue: out[b][h*64+d][i], d = dt*32 + (r&3)+8*(r>>2)+4*hi ----
  float inv = 1.f / lsum;
  size_t obase = ((size_t)b * Cn + h * 64) * Ln + qb + il;
#pragma unroll
  for (int dt = 0; dt < 2; ++dt)
#pragma unroll
    for (int r = 0; r < 16; ++r) {
      int d = dt * 32 + (r & 3) + 8 * (r >> 2) + 4 * hi;
      out[obase + (size_t)d * Ln] = acc[dt][r] * inv;
    }
}

extern "C" void kernel_launch(void* const* d_in, const int* in_sizes, int n_in,
                              void* d_out, int out_size, void* d_ws, size_t ws_size,
                              hipStream_t stream) {
  const float* queries = (const float*)d_in[0];
  const int*   mask    = (const int*)d_in[1];
  const float* Wm      = (const float*)d_in[2];
  const float* Wq      = (const float*)d_in[3];
  float* out = (float*)d_out;
  char* ws = (char*)d_ws;
  f16* Xt = (f16*)(ws);
  f16* Qd = (f16*)(ws + 8388608);
  f16* Kd = (f16*)(ws + 16777216);
  f16* Vv = (f16*)(ws + 25165824);

  k_transpose<<<1024, 256, 0, stream>>>(queries, Xt);
  k_proj<<<768, 256, 0, stream>>>(Wq, Wm, Xt, Qd, Kd, Vv);
  k_attn<<<512, 256, 0, stream>>>(Qd, Kd, Vv, mask, out);
}

// Round 5
// 145.611 us; speedup vs baseline: 2.0874x; 1.0020x over previous
//
#include <hip/hip_runtime.h>

#define Bn 2
#define Cn 512
#define Ln 4096
#define Hn 8
#define Dn 64

typedef _Float16 f16;
typedef _Float16 h8 __attribute__((ext_vector_type(8)));
typedef _Float16 h4 __attribute__((ext_vector_type(4)));
typedef float f32x4 __attribute__((ext_vector_type(4)));
typedef float f32x16 __attribute__((ext_vector_type(16)));

#define MFMA32(a, b, c) __builtin_amdgcn_mfma_f32_16x16x32_f16(a, b, c, 0, 0, 0)
#define MFMA3216(a, b, c) __builtin_amdgcn_mfma_f32_32x32x16_f16(a, b, c, 0, 0, 0)
#define AS1(p) ((const __attribute__((address_space(1))) void*)(p))
#define AS3(p) ((__attribute__((address_space(3))) void*)(p))

// ---------------- kernel 1: X [B][C][L] f32 -> Xt [B][L][C] f16 ----------------
__global__ __launch_bounds__(256) void k_transpose(const float* __restrict__ X,
                                                   f16* __restrict__ Xt) {
  int bid = blockIdx.x;
  int b  = bid >> 9;
  int r  = bid & 511;
  int lt = r >> 3, ct = r & 7;
  int l0 = lt << 6, c0 = ct << 6;
  __shared__ f16 t[64][66];
  int tid = threadIdx.x;
  int lx = tid & 63, cg = tid >> 6;
  const float* xb = X + ((size_t)b * Cn) * Ln;
#pragma unroll
  for (int rr = 0; rr < 16; ++rr) {
    int cl = cg * 16 + rr;
    t[lx][cl] = (f16)xb[(size_t)(c0 + cl) * Ln + l0 + lx];
  }
  __syncthreads();
  f16* xo = Xt + ((size_t)b * Ln + l0) * Cn + c0;
  int cx = tid & 63, lg = tid >> 6;
#pragma unroll
  for (int rr = 0; rr < 16; ++rr) {
    int ll = lg * 16 + rr;
    xo[(size_t)ll * Cn + cx] = t[ll][cx];
  }
}

// ---------------- kernel 2: projection GEMM (unchanged) ----------------
__global__ __launch_bounds__(256) void k_proj(const float* __restrict__ Wq,
                                              const float* __restrict__ Wm,
                                              const f16* __restrict__ Xt,
                                              f16* __restrict__ Qd,
                                              f16* __restrict__ Kd,
                                              f16* __restrict__ Vv) {
  int bid = blockIdx.x;
  int b = bid / 384;
  int r = bid % 384;
  int mt = r >> 5, nt = r & 31;
  int o0 = mt << 7, l0 = nt << 7;
  __shared__ f16 a_lds[128][40];
  __shared__ f16 b_lds[128][40];
  int tid = threadIdx.x;
  int lane = tid & 63, w = tid >> 6;
  int wr = w >> 1, wc = w & 1;
  f32x4 acc[4][4] = {};

  int sr = tid >> 1;
  int scg = (tid & 1) << 4;
  int o_s = o0 + sr;
  const float* wrow = (o_s < 512) ? (Wq + (size_t)o_s * Cn)
                                  : (Wm + (size_t)(o_s - 512) * Cn);
  const f16* xrow = Xt + ((size_t)b * Ln + l0 + sr) * Cn;

  for (int kt = 0; kt < 16; ++kt) {
    int c0 = kt << 5;
    __syncthreads();
#pragma unroll
    for (int i = 0; i < 4; ++i) {
      float4 w4 = *(const float4*)(wrow + c0 + scg + 4 * i);
      h4 hh = { (f16)w4.x, (f16)w4.y, (f16)w4.z, (f16)w4.w };
      *(h4*)&a_lds[sr][scg + 4 * i] = hh;
    }
#pragma unroll
    for (int i = 0; i < 2; ++i)
      *(h8*)&b_lds[sr][scg + 8 * i] = *(const h8*)(xrow + c0 + scg + 8 * i);
    __syncthreads();

    h8 af[4], bf[4];
#pragma unroll
    for (int mi = 0; mi < 4; ++mi)
      af[mi] = *(const h8*)&a_lds[wr * 64 + mi * 16 + (lane & 15)][(lane >> 4) * 8];
#pragma unroll
    for (int ni = 0; ni < 4; ++ni)
      bf[ni] = *(const h8*)&b_lds[wc * 64 + ni * 16 + (lane & 15)][(lane >> 4) * 8];
#pragma unroll
    for (int mi = 0; mi < 4; ++mi)
#pragma unroll
      for (int ni = 0; ni < 4; ++ni)
        acc[mi][ni] = MFMA32(af[mi], bf[ni], acc[mi][ni]);
  }

  const float QSCALE = 0.18033688011112042f;   // 2^-3 * log2(e)
  int lrow = (lane >> 4) << 2;
  int lcol = lane & 15;
#pragma unroll
  for (int mi = 0; mi < 4; ++mi) {
    int ob = o0 + wr * 64 + mi * 16 + lrow;
#pragma unroll
    for (int ni = 0; ni < 4; ++ni) {
      int lc = l0 + wc * 64 + ni * 16 + lcol;
      f32x4 a = acc[mi][ni];
      if (ob < 512) {
        int h = ob >> 6, d = ob & 63;
        h4 hh = { (f16)(a[0] * QSCALE), (f16)(a[1] * QSCALE),
                  (f16)(a[2] * QSCALE), (f16)(a[3] * QSCALE) };
        *(h4*)&Qd[(((size_t)b * Hn + h) * Ln + lc) * Dn + d] = hh;
      } else if (ob < 1024) {
        int oc = ob - 512;
        int h = oc >> 6, d = oc & 63;
        h4 hh = { (f16)a[0], (f16)a[1], (f16)a[2], (f16)a[3] };
        *(h4*)&Kd[(((size_t)b * Hn + h) * Ln + lc) * Dn + d] = hh;
      } else {
        int oc = ob - 1024;
#pragma unroll
        for (int rr = 0; rr < 4; ++rr)
          Vv[((size_t)b * Cn + oc + rr) * Ln + lc] = (f16)a[rr];
      }
    }
  }
}

// ---------------- kernel 3: flash attention, pipelined 32x32x16 ----------------
// grid 512 (XCD-swizzled). Block = 4 waves x 32 q. 4 LDS tile-buffers (64 KB),
// staging 3 tiles ahead; 1 barrier + counted vmcnt(4) per iter.
// Body t: STAGE(t+3) | QK(t+1) [MFMA] interleaved w/ softmax(t) [VALU] | PV(t).
__global__ __launch_bounds__(256, 2) void k_attn(const f16* __restrict__ Qd,
                                                 const f16* __restrict__ Kd,
                                                 const f16* __restrict__ Vv,
                                                 const int* __restrict__ mask,
                                                 float* __restrict__ out) {
  int bid0 = blockIdx.x;
  int bid = (bid0 & 7) * 64 + (bid0 >> 3);   // T1: 64 blocks (2 bh) per XCD
  int bh = bid >> 5, ib = bid & 31;
  int b = bh >> 3, h = bh & 7;
  int tid = threadIdx.x;
  int lane = tid & 63, w = tid >> 6;
  int il = lane & 31, hi = lane >> 5;

  // [64 rows][8 chunks of 16B]; logical chunk u of row r lives at phys u^(r&7)
  __shared__ __align__(16) f16 kbuf[4][64 * 64];
  __shared__ __align__(16) f16 vbuf[4][64 * 64];

  int qb = ib * 128 + w * 32;
  const f16* qp = Qd + ((size_t)bh * Ln + qb + il) * Dn;
  h8 qreg[4];
#pragma unroll
  for (int dt = 0; dt < 4; ++dt)
    qreg[dt] = *(const h8*)(qp + dt * 16 + hi * 8);

  // per-64-block all-ones mask flags
  const int* mbase = mask + (size_t)b * Ln;
  unsigned long long flags;
  {
    const int4* mp = (const int4*)mbase + lane * 16;
    int ac = 1;
#pragma unroll
    for (int q = 0; q < 16; ++q) { int4 v = mp[q]; ac &= v.x & v.y & v.z & v.w; }
    flags = __ballot(ac == 1);
  }

  const f16* kbase = Kd + (size_t)bh * Ln * Dn;
  const f16* vbase = Vv + ((size_t)b * Cn + h * 64) * Ln;
  int koff[2], voff[2];
#pragma unroll
  for (int q = 0; q < 2; ++q) {
    int rr = w * 16 + q * 8 + (lane >> 3);
    int swz = (lane & 7) ^ (rr & 7);
    koff[q] = rr * 64 + swz * 8;
    voff[q] = rr * Ln + swz * 8;
  }

#define STAGE(bi, t)                                                            \
  {                                                                             \
    _Pragma("unroll")                                                           \
    for (int q = 0; q < 2; ++q) {                                               \
      __builtin_amdgcn_global_load_lds(AS1(kbase + (size_t)(t) * 4096 + koff[q]),\
                                       AS3(&kbuf[bi][(w * 16 + q * 8) * 64]),   \
                                       16, 0, 0);                               \
      __builtin_amdgcn_global_load_lds(AS1(vbase + (size_t)(t) * 64 + voff[q]), \
                                       AS3(&vbuf[bi][(w * 16 + q * 8) * 64]),   \
                                       16, 0, 0);                               \
    }                                                                           \
  }

  f32x16 acc0 = {}, acc1 = {};  // O^T: col=i=il, row d = dt*32 + (r&3)+8*(r>>2)+4*hi
  float mrow = -1e38f;
  float lsum = 0.f;
  int swz7 = il & 7;

#define QK_TILE(KL, SN0, SN1)                                    \
  {                                                              \
    const f16* kl_ = (KL);                                       \
    f32x16 z0 = {}, z1 = {};                                     \
    _Pragma("unroll")                                            \
    for (int dt = 0; dt < 4; ++dt) {                             \
      int c = ((dt * 2 + hi) ^ swz7) << 3;                       \
      h8 ak0 = *(const h8*)&kl_[il * 64 + c];                    \
      h8 ak1 = *(const h8*)&kl_[(32 + il) * 64 + c];             \
      z0 = MFMA3216(ak0, qreg[dt], z0);                          \
      z1 = MFMA3216(ak1, qreg[dt], z1);                          \
    }                                                            \
    SN0 = z0; SN1 = z1;                                          \
  }

#define MASK_FIX(tt, S0, S1)                                     \
  if (!((flags >> (tt)) & 1)) {                                  \
    _Pragma("unroll")                                            \
    for (int r = 0; r < 16; ++r) {                               \
      int j = (tt) * 64 + (r & 3) + 8 * (r >> 2) + 4 * hi;       \
      if (!mbase[j])      S0[r] = -3.0e4f;                       \
      if (!mbase[j + 32]) S1[r] = -3.0e4f;                       \
    }                                                            \
  }

#define SOFTMAX_PV(tt, S0, S1)                                                  \
  {                                                                             \
    float m0 = fmaxf(fmaxf(S0[0], S0[1]), fmaxf(S0[2], S0[3]));                 \
    float m1 = fmaxf(fmaxf(S0[4], S0[5]), fmaxf(S0[6], S0[7]));                 \
    float m2 = fmaxf(fmaxf(S0[8], S0[9]), fmaxf(S0[10], S0[11]));               \
    float m3 = fmaxf(fmaxf(S0[12], S0[13]), fmaxf(S0[14], S0[15]));             \
    float m4 = fmaxf(fmaxf(S1[0], S1[1]), fmaxf(S1[2], S1[3]));                 \
    float m5 = fmaxf(fmaxf(S1[4], S1[5]), fmaxf(S1[6], S1[7]));                 \
    float m6 = fmaxf(fmaxf(S1[8], S1[9]), fmaxf(S1[10], S1[11]));               \
    float m7 = fmaxf(fmaxf(S1[12], S1[13]), fmaxf(S1[14], S1[15]));             \
    float mx = fmaxf(fmaxf(fmaxf(m0, m1), fmaxf(m2, m3)),                       \
                     fmaxf(fmaxf(m4, m5), fmaxf(m6, m7)));                      \
    mx = fmaxf(mx, __shfl_xor(mx, 32));                                         \
    if (__any(mx > mrow + 8.f)) {      /* T13 defer-max, THR=8 */               \
      float mn = fmaxf(mrow, mx);                                               \
      float al = __builtin_amdgcn_exp2f(mrow - mn);                             \
      lsum *= al;                                                               \
      _Pragma("unroll")                                                         \
      for (int r = 0; r < 16; ++r) { acc0[r] *= al; acc1[r] *= al; }            \
      mrow = mn;                                                                \
    }                                                                           \
    _Pragma("unroll")                                                           \
    for (int r = 0; r < 16; ++r) {                                              \
      S0[r] = __builtin_amdgcn_exp2f(S0[r] - mrow);                             \
      S1[r] = __builtin_amdgcn_exp2f(S1[r] - mrow);                             \
    }                                                                           \
    {  /* balanced sum tree, depth 5 */                                         \
      float a0 = (S0[0] + S0[1]) + (S0[2] + S0[3]);                             \
      float a1 = (S0[4] + S0[5]) + (S0[6] + S0[7]);                             \
      float a2 = (S0[8] + S0[9]) + (S0[10] + S0[11]);                           \
      float a3 = (S0[12] + S0[13]) + (S0[14] + S0[15]);                         \
      float a4 = (S1[0] + S1[1]) + (S1[2] + S1[3]);                             \
      float a5 = (S1[4] + S1[5]) + (S1[6] + S1[7]);                             \
      float a6 = (S1[8] + S1[9]) + (S1[10] + S1[11]);                           \
      float a7 = (S1[12] + S1[13]) + (S1[14] + S1[15]);                         \
      float rs = ((a0 + a1) + (a2 + a3)) + ((a4 + a5) + (a6 + a7));             \
      rs += __shfl_xor(rs, 32);                                                 \
      lsum += rs;                                                               \
    }                                                                           \
    float dw0[8], dw1[8];                                                       \
    _Pragma("unroll")                                                           \
    for (int r = 0; r < 16; r += 2) {                                           \
      dw0[r >> 1] = __builtin_bit_cast(float,                                   \
          __builtin_amdgcn_cvt_pkrtz(S0[r], S0[r + 1]));                        \
      dw1[r >> 1] = __builtin_bit_cast(float,                                   \
          __builtin_amdgcn_cvt_pkrtz(S1[r], S1[r + 1]));                        \
    }                                                                           \
    h8 pb[4];                                                                   \
    _Pragma("unroll")                                                           \
    for (int jt = 0; jt < 4; ++jt) {                                            \
      const float* dd = (jt < 2) ? dw0 : dw1;                                   \
      int base = (jt & 1) * 4;                                                  \
      float x0 = dd[base + 0], x1 = dd[base + 1];                               \
      float y0 = dd[base + 2], y1 = dd[base + 3];                               \
      float v0 = hi ? x0 : y0, v1 = hi ? x1 : y1;                               \
      float p0 = __shfl_xor(v0, 32), p1 = __shfl_xor(v1, 32);                   \
      union { h8 v; float f[4]; } u;                                            \
      u.f[0] = hi ? p0 : x0;                                                    \
      u.f[1] = hi ? p1 : x1;                                                    \
      u.f[2] = hi ? y0 : p0;                                                    \
      u.f[3] = hi ? y1 : p1;                                                    \
      pb[jt] = u.v;                                                             \
    }                                                                           \
    const f16* vl_ = &vbuf[(tt) & 3][0];                                        \
    __builtin_amdgcn_s_setprio(1);                                              \
    _Pragma("unroll")                                                           \
    for (int dt = 0; dt < 2; ++dt) {                                            \
      int rv = dt * 32 + il;                                                    \
      _Pragma("unroll")                                                         \
      for (int jt = 0; jt < 4; ++jt) {                                          \
        h8 av = *(const h8*)&vl_[rv * 64 + (((jt * 2 + hi) ^ swz7) << 3)];      \
        if (dt == 0) acc0 = MFMA3216(av, pb[jt], acc0);                         \
        else         acc1 = MFMA3216(av, pb[jt], acc1);                         \
      }                                                                         \
    }                                                                           \
    __builtin_amdgcn_s_setprio(0);                                              \
  }

#define BODY(tt, SC0, SC1, SN0, SN1)                                            \
  {                                                                             \
    asm volatile("s_waitcnt vmcnt(4)" ::: "memory");                            \
    __builtin_amdgcn_s_barrier();                                               \
    if ((tt) + 3 < 64) STAGE(((tt) + 3) & 3, (tt) + 3);                         \
    QK_TILE(&kbuf[((tt) + 1) & 3][0], SN0, SN1);                                \
    MASK_FIX((tt) + 1, SN0, SN1);                                               \
    SOFTMAX_PV(tt, SC0, SC1);                                                   \
  }

  // prologue: stage 3 tiles, compute S(0)
  STAGE(0, 0);
  STAGE(1, 1);
  STAGE(2, 2);
  asm volatile("s_waitcnt vmcnt(8)" ::: "memory");
  __builtin_amdgcn_s_barrier();
  f32x16 sE0, sE1, sO0, sO1;
  QK_TILE(&kbuf[0][0], sE0, sE1);
  MASK_FIX(0, sE0, sE1);

  for (int t = 0; t < 62; t += 2) {
    BODY(t, sE0, sE1, sO0, sO1);
    BODY(t + 1, sO0, sO1, sE0, sE1);
  }
  // peeled t = 62: only STAGE(63) may be outstanding -> drain fully
  {
    asm volatile("s_waitcnt vmcnt(0)" ::: "memory");
    __builtin_amdgcn_s_barrier();
    QK_TILE(&kbuf[3][0], sO0, sO1);
    MASK_FIX(63, sO0, sO1);
    SOFTMAX_PV(62, sE0, sE1);
  }
  // tail t = 63
  SOFTMAX_PV(63, sO0, sO1);

  // ---- epilogue: out[b][h*64+d][i], d = dt*32 + (r&3)+8*(r>>2)+4*hi ----
  float inv = 1.f / lsum;
  size_t obase = ((size_t)b * Cn + h * 64) * Ln + qb + il;
#pragma unroll
  for (int r = 0; r < 16; ++r) {
    int d0 = (r & 3) + 8 * (r >> 2) + 4 * hi;
    out[obase + (size_t)d0 * Ln] = acc0[r] * inv;
    out[obase + (size_t)(d0 + 32) * Ln] = acc1[r] * inv;
  }
}

extern "C" void kernel_launch(void* const* d_in, const int* in_sizes, int n_in,
                              void* d_out, int out_size, void* d_ws, size_t ws_size,
                              hipStream_t stream) {
  const float* queries = (const float*)d_in[0];
  const int*   mask    = (const int*)d_in[1];
  const float* Wm      = (const float*)d_in[2];
  const float* Wq      = (const float*)d_in[3];
  float* out = (float*)d_out;
  char* ws = (char*)d_ws;
  f16* Xt = (f16*)(ws);
  f16* Qd = (f16*)(ws + 8388608);
  f16* Kd = (f16*)(ws + 16777216);
  f16* Vv = (f16*)(ws + 25165824);

  k_transpose<<<1024, 256, 0, stream>>>(queries, Xt);
  k_proj<<<768, 256, 0, stream>>>(Wq, Wm, Xt, Qd, Kd, Vv);
  k_attn<<<512, 256, 0, stream>>>(Qd, Kd, Vv, mask, out);
}

// Round 6
// 140.570 us; speedup vs baseline: 2.1623x; 1.0359x over previous
//
#include <hip/hip_runtime.h>

#define Bn 2
#define Cn 512
#define Ln 4096
#define Hn 8
#define Dn 64

typedef _Float16 f16;
typedef _Float16 h8 __attribute__((ext_vector_type(8)));
typedef _Float16 h4 __attribute__((ext_vector_type(4)));
typedef float f32x4 __attribute__((ext_vector_type(4)));
typedef float f32x16 __attribute__((ext_vector_type(16)));

#define MFMA32(a, b, c) __builtin_amdgcn_mfma_f32_16x16x32_f16(a, b, c, 0, 0, 0)
#define MFMA3216(a, b, c) __builtin_amdgcn_mfma_f32_32x32x16_f16(a, b, c, 0, 0, 0)
#define AS1(p) ((const __attribute__((address_space(1))) void*)(p))
#define AS3(p) ((__attribute__((address_space(3))) void*)(p))

// ---------------- kernel 1: X [B][C][L] f32 -> Xt [B][L][C] f16 ----------------
__global__ __launch_bounds__(256) void k_transpose(const float* __restrict__ X,
                                                   f16* __restrict__ Xt) {
  int bid = blockIdx.x;
  int b  = bid >> 9;
  int r  = bid & 511;
  int lt = r >> 3, ct = r & 7;
  int l0 = lt << 6, c0 = ct << 6;
  __shared__ f16 t[64][66];
  int tid = threadIdx.x;
  int lx = tid & 63, cg = tid >> 6;
  const float* xb = X + ((size_t)b * Cn) * Ln;
#pragma unroll
  for (int rr = 0; rr < 16; ++rr) {
    int cl = cg * 16 + rr;
    t[lx][cl] = (f16)xb[(size_t)(c0 + cl) * Ln + l0 + lx];
  }
  __syncthreads();
  f16* xo = Xt + ((size_t)b * Ln + l0) * Cn + c0;
  int cx = tid & 63, lg = tid >> 6;
#pragma unroll
  for (int rr = 0; rr < 16; ++rr) {
    int ll = lg * 16 + rr;
    xo[(size_t)ll * Cn + cx] = t[ll][cx];
  }
}

// ---------------- kernel 2: projection GEMM (unchanged) ----------------
__global__ __launch_bounds__(256) void k_proj(const float* __restrict__ Wq,
                                              const float* __restrict__ Wm,
                                              const f16* __restrict__ Xt,
                                              f16* __restrict__ Qd,
                                              f16* __restrict__ Kd,
                                              f16* __restrict__ Vv) {
  int bid = blockIdx.x;
  int b = bid / 384;
  int r = bid % 384;
  int mt = r >> 5, nt = r & 31;
  int o0 = mt << 7, l0 = nt << 7;
  __shared__ f16 a_lds[128][40];
  __shared__ f16 b_lds[128][40];
  int tid = threadIdx.x;
  int lane = tid & 63, w = tid >> 6;
  int wr = w >> 1, wc = w & 1;
  f32x4 acc[4][4] = {};

  int sr = tid >> 1;
  int scg = (tid & 1) << 4;
  int o_s = o0 + sr;
  const float* wrow = (o_s < 512) ? (Wq + (size_t)o_s * Cn)
                                  : (Wm + (size_t)(o_s - 512) * Cn);
  const f16* xrow = Xt + ((size_t)b * Ln + l0 + sr) * Cn;

  for (int kt = 0; kt < 16; ++kt) {
    int c0 = kt << 5;
    __syncthreads();
#pragma unroll
    for (int i = 0; i < 4; ++i) {
      float4 w4 = *(const float4*)(wrow + c0 + scg + 4 * i);
      h4 hh = { (f16)w4.x, (f16)w4.y, (f16)w4.z, (f16)w4.w };
      *(h4*)&a_lds[sr][scg + 4 * i] = hh;
    }
#pragma unroll
    for (int i = 0; i < 2; ++i)
      *(h8*)&b_lds[sr][scg + 8 * i] = *(const h8*)(xrow + c0 + scg + 8 * i);
    __syncthreads();

    h8 af[4], bf[4];
#pragma unroll
    for (int mi = 0; mi < 4; ++mi)
      af[mi] = *(const h8*)&a_lds[wr * 64 + mi * 16 + (lane & 15)][(lane >> 4) * 8];
#pragma unroll
    for (int ni = 0; ni < 4; ++ni)
      bf[ni] = *(const h8*)&b_lds[wc * 64 + ni * 16 + (lane & 15)][(lane >> 4) * 8];
#pragma unroll
    for (int mi = 0; mi < 4; ++mi)
#pragma unroll
      for (int ni = 0; ni < 4; ++ni)
        acc[mi][ni] = MFMA32(af[mi], bf[ni], acc[mi][ni]);
  }

  const float QSCALE = 0.18033688011112042f;   // 2^-3 * log2(e)
  int lrow = (lane >> 4) << 2;
  int lcol = lane & 15;
#pragma unroll
  for (int mi = 0; mi < 4; ++mi) {
    int ob = o0 + wr * 64 + mi * 16 + lrow;
#pragma unroll
    for (int ni = 0; ni < 4; ++ni) {
      int lc = l0 + wc * 64 + ni * 16 + lcol;
      f32x4 a = acc[mi][ni];
      if (ob < 512) {
        int h = ob >> 6, d = ob & 63;
        h4 hh = { (f16)(a[0] * QSCALE), (f16)(a[1] * QSCALE),
                  (f16)(a[2] * QSCALE), (f16)(a[3] * QSCALE) };
        *(h4*)&Qd[(((size_t)b * Hn + h) * Ln + lc) * Dn + d] = hh;
      } else if (ob < 1024) {
        int oc = ob - 512;
        int h = oc >> 6, d = oc & 63;
        h4 hh = { (f16)a[0], (f16)a[1], (f16)a[2], (f16)a[3] };
        *(h4*)&Kd[(((size_t)b * Hn + h) * Ln + lc) * Dn + d] = hh;
      } else {
        int oc = ob - 1024;
#pragma unroll
        for (int rr = 0; rr < 4; ++rr)
          Vv[((size_t)b * Cn + oc + rr) * Ln + lc] = (f16)a[rr];
      }
    }
  }
}

// ---------------- kernel 3: flash attention, 2-way KV split in block ----------------
// grid 512 (XCD-swizzled), block = 8 waves (512 thr). Group g = waves 4g..4g+3
// processes KV half g (32 tiles) for the same 128 q-rows; merge via LDS.
// 4 waves/SIMD occupancy; 2-deep LDS double-buffer per group (64 KB total).
__global__ __launch_bounds__(512, 4) void k_attn(const f16* __restrict__ Qd,
                                                 const f16* __restrict__ Kd,
                                                 const f16* __restrict__ Vv,
                                                 const int* __restrict__ mask,
                                                 float* __restrict__ out) {
  int bid0 = blockIdx.x;
  int bid = (bid0 & 7) * 64 + (bid0 >> 3);   // T1: 64 blocks (2 bh) per XCD
  int bh = bid >> 5, ib = bid & 31;
  int b = bh >> 3, h = bh & 7;
  int tid = threadIdx.x;
  int lane = tid & 63, w = tid >> 6;
  int grp = w >> 2, wq = w & 3;
  int il = lane & 31, hi = lane >> 5;

  // 64 KB: [grp][dbuf] K then V tiles, each 64x64 f16 (rows swizzled by chunk^row&7)
  __shared__ __align__(16) f16 smem[8 * 4096];
#define KBUF(g, bi) (&smem[(((g) * 2 + (bi))) * 4096])
#define VBUF(g, bi) (&smem[((4 + (g) * 2 + (bi))) * 4096])

  int qb = ib * 128 + wq * 32;
  const f16* qp = Qd + ((size_t)bh * Ln + qb + il) * Dn;
  h8 qreg[4];
#pragma unroll
  for (int dt = 0; dt < 4; ++dt)
    qreg[dt] = *(const h8*)(qp + dt * 16 + hi * 8);

  // per-64-block all-ones mask flags (all 64 tiles)
  const int* mbase = mask + (size_t)b * Ln;
  unsigned long long flags;
  {
    const int4* mp = (const int4*)mbase + lane * 16;
    int ac = 1;
#pragma unroll
    for (int q = 0; q < 16; ++q) { int4 v = mp[q]; ac &= v.x & v.y & v.z & v.w; }
    flags = __ballot(ac == 1);
  }

  const f16* kbase = Kd + (size_t)bh * Ln * Dn + (size_t)grp * 32 * 4096;
  const f16* vbase = Vv + ((size_t)b * Cn + h * 64) * Ln + grp * 32 * 64;
  int koff[2], voff[2];
#pragma unroll
  for (int q = 0; q < 2; ++q) {
    int rr = wq * 16 + q * 8 + (lane >> 3);
    int swz = (lane & 7) ^ (rr & 7);
    koff[q] = rr * 64 + swz * 8;
    voff[q] = rr * Ln + swz * 8;
  }

#define STAGE(bi, t)                                                            \
  {                                                                             \
    _Pragma("unroll")                                                           \
    for (int q = 0; q < 2; ++q) {                                               \
      __builtin_amdgcn_global_load_lds(AS1(kbase + (size_t)(t) * 4096 + koff[q]),\
                                       AS3(KBUF(grp, bi) + (wq * 16 + q * 8) * 64),\
                                       16, 0, 0);                               \
      __builtin_amdgcn_global_load_lds(AS1(vbase + (size_t)(t) * 64 + voff[q]), \
                                       AS3(VBUF(grp, bi) + (wq * 16 + q * 8) * 64),\
                                       16, 0, 0);                               \
    }                                                                           \
  }

  f32x16 acc0 = {}, acc1 = {};  // O^T: col=i=il, row d = dt*32 + (r&3)+8*(r>>2)+4*hi
  float mrow = -1e38f;
  float lsum = 0.f;
  int swz7 = il & 7;

  STAGE(0, 0);
  STAGE(1, 1);

#define BODY(t_, waitn_)                                                        \
  {                                                                             \
    asm volatile("s_waitcnt vmcnt(" waitn_ ")" ::: "memory");                   \
    __builtin_amdgcn_s_barrier();                                               \
    const f16* kl_ = KBUF(grp, (t_) & 1);                                       \
    f32x16 s0 = {}, s1 = {};                                                    \
    __builtin_amdgcn_s_setprio(1);                                              \
    _Pragma("unroll")                                                           \
    for (int dt = 0; dt < 4; ++dt) {                                            \
      int c = ((dt * 2 + hi) ^ swz7) << 3;                                      \
      h8 ak0 = *(const h8*)&kl_[il * 64 + c];                                   \
      h8 ak1 = *(const h8*)&kl_[(32 + il) * 64 + c];                            \
      s0 = MFMA3216(ak0, qreg[dt], s0);                                         \
      s1 = MFMA3216(ak1, qreg[dt], s1);                                         \
    }                                                                           \
    __builtin_amdgcn_s_setprio(0);                                              \
    int T_ = grp * 32 + (t_);                                                   \
    if (!((flags >> T_) & 1)) {                                                 \
      _Pragma("unroll")                                                         \
      for (int r = 0; r < 16; ++r) {                                            \
        int j = T_ * 64 + (r & 3) + 8 * (r >> 2) + 4 * hi;                      \
        if (!mbase[j])      s0[r] = -3.0e4f;                                    \
        if (!mbase[j + 32]) s1[r] = -3.0e4f;                                    \
      }                                                                         \
    }                                                                           \
    float m0 = fmaxf(fmaxf(s0[0], s0[1]), fmaxf(s0[2], s0[3]));                 \
    float m1 = fmaxf(fmaxf(s0[4], s0[5]), fmaxf(s0[6], s0[7]));                 \
    float m2 = fmaxf(fmaxf(s0[8], s0[9]), fmaxf(s0[10], s0[11]));               \
    float m3 = fmaxf(fmaxf(s0[12], s0[13]), fmaxf(s0[14], s0[15]));             \
    float m4 = fmaxf(fmaxf(s1[0], s1[1]), fmaxf(s1[2], s1[3]));                 \
    float m5 = fmaxf(fmaxf(s1[4], s1[5]), fmaxf(s1[6], s1[7]));                 \
    float m6 = fmaxf(fmaxf(s1[8], s1[9]), fmaxf(s1[10], s1[11]));               \
    float m7 = fmaxf(fmaxf(s1[12], s1[13]), fmaxf(s1[14], s1[15]));             \
    float mx = fmaxf(fmaxf(fmaxf(m0, m1), fmaxf(m2, m3)),                       \
                     fmaxf(fmaxf(m4, m5), fmaxf(m6, m7)));                      \
    mx = fmaxf(mx, __shfl_xor(mx, 32));                                         \
    if (__any(mx > mrow + 8.f)) {      /* T13 defer-max, THR=8 */               \
      float mn = fmaxf(mrow, mx);                                               \
      float al = __builtin_amdgcn_exp2f(mrow - mn);                             \
      lsum *= al;                                                               \
      _Pragma("unroll")                                                         \
      for (int r = 0; r < 16; ++r) { acc0[r] *= al; acc1[r] *= al; }            \
      mrow = mn;                                                                \
    }                                                                           \
    _Pragma("unroll")                                                           \
    for (int r = 0; r < 16; ++r) {                                              \
      s0[r] = __builtin_amdgcn_exp2f(s0[r] - mrow);                             \
      s1[r] = __builtin_amdgcn_exp2f(s1[r] - mrow);                             \
    }                                                                           \
    {  /* balanced sum tree */                                                  \
      float a0 = (s0[0] + s0[1]) + (s0[2] + s0[3]);                             \
      float a1 = (s0[4] + s0[5]) + (s0[6] + s0[7]);                             \
      float a2 = (s0[8] + s0[9]) + (s0[10] + s0[11]);                           \
      float a3 = (s0[12] + s0[13]) + (s0[14] + s0[15]);                         \
      float a4 = (s1[0] + s1[1]) + (s1[2] + s1[3]);                             \
      float a5 = (s1[4] + s1[5]) + (s1[6] + s1[7]);                             \
      float a6 = (s1[8] + s1[9]) + (s1[10] + s1[11]);                           \
      float a7 = (s1[12] + s1[13]) + (s1[14] + s1[15]);                         \
      float rs = ((a0 + a1) + (a2 + a3)) + ((a4 + a5) + (a6 + a7));             \
      rs += __shfl_xor(rs, 32);                                                 \
      lsum += rs;                                                               \
    }                                                                           \
    float dw0[8], dw1[8];                                                       \
    _Pragma("unroll")                                                           \
    for (int r = 0; r < 16; r += 2) {                                           \
      dw0[r >> 1] = __builtin_bit_cast(float,                                   \
          __builtin_amdgcn_cvt_pkrtz(s0[r], s0[r + 1]));                        \
      dw1[r >> 1] = __builtin_bit_cast(float,                                   \
          __builtin_amdgcn_cvt_pkrtz(s1[r], s1[r + 1]));                        \
    }                                                                           \
    h8 pb[4];                                                                   \
    _Pragma("unroll")                                                           \
    for (int jt = 0; jt < 4; ++jt) {                                            \
      const float* dd = (jt < 2) ? dw0 : dw1;                                   \
      int base = (jt & 1) * 4;                                                  \
      float x0 = dd[base + 0], x1 = dd[base + 1];                               \
      float y0 = dd[base + 2], y1 = dd[base + 3];                               \
      float v0 = hi ? x0 : y0, v1 = hi ? x1 : y1;                               \
      float p0 = __shfl_xor(v0, 32), p1 = __shfl_xor(v1, 32);                   \
      union { h8 v; float f[4]; } u;                                            \
      u.f[0] = hi ? p0 : x0;                                                    \
      u.f[1] = hi ? p1 : x1;                                                    \
      u.f[2] = hi ? y0 : p0;                                                    \
      u.f[3] = hi ? y1 : p1;                                                    \
      pb[jt] = u.v;                                                             \
    }                                                                           \
    const f16* vl_ = VBUF(grp, (t_) & 1);                                       \
    __builtin_amdgcn_s_setprio(1);                                              \
    _Pragma("unroll")                                                           \
    for (int dt = 0; dt < 2; ++dt) {                                            \
      int rv = dt * 32 + il;                                                    \
      _Pragma("unroll")                                                         \
      for (int jt = 0; jt < 4; ++jt) {                                          \
        h8 av = *(const h8*)&vl_[rv * 64 + (((jt * 2 + hi) ^ swz7) << 3)];      \
        if (dt == 0) acc0 = MFMA3216(av, pb[jt], acc0);                         \
        else         acc1 = MFMA3216(av, pb[jt], acc1);                         \
      }                                                                         \
    }                                                                           \
    __builtin_amdgcn_s_setprio(0);                                              \
    __builtin_amdgcn_s_barrier();                                               \
    if ((t_) < 30) STAGE((t_) & 1, (t_) + 2);                                   \
  }

  for (int t = 0; t < 31; ++t) {
    BODY(t, "4");
  }
  BODY(31, "0");

  // ---- merge the two KV halves via LDS (padded stride-33 to dodge conflicts) ----
  __syncthreads();
  float* shf = (float*)smem;
  if (grp == 1) {
    float* basep = shf + wq * (64 * 33) + lane * 33;
#pragma unroll
    for (int r = 0; r < 16; ++r) { basep[r] = acc0[r]; basep[16 + r] = acc1[r]; }
    float* ml = shf + 4 * 64 * 33 + (wq * 64 + lane) * 2;
    ml[0] = mrow; ml[1] = lsum;
  }
  __syncthreads();
  if (grp == 0) {
    float* basep = shf + wq * (64 * 33) + lane * 33;
    float* ml = shf + 4 * 64 * 33 + (wq * 64 + lane) * 2;
    float mB = ml[0], lB = ml[1];
    float M = fmaxf(mrow, mB);
    float wA = __builtin_amdgcn_exp2f(mrow - M);
    float wB = __builtin_amdgcn_exp2f(mB - M);
    float linv = 1.f / (lsum * wA + lB * wB);
    float fA = wA * linv, fB = wB * linv;
    size_t obase = ((size_t)b * Cn + h * 64) * Ln + qb + il;
#pragma unroll
    for (int r = 0; r < 16; ++r) {
      int d0 = (r & 3) + 8 * (r >> 2) + 4 * hi;
      out[obase + (size_t)d0 * Ln] = acc0[r] * fA + basep[r] * fB;
      out[obase + (size_t)(d0 + 32) * Ln] = acc1[r] * fA + basep[16 + r] * fB;
    }
  }
}

extern "C" void kernel_launch(void* const* d_in, const int* in_sizes, int n_in,
                              void* d_out, int out_size, void* d_ws, size_t ws_size,
                              hipStream_t stream) {
  const float* queries = (const float*)d_in[0];
  const int*   mask    = (const int*)d_in[1];
  const float* Wm      = (const float*)d_in[2];
  const float* Wq      = (const float*)d_in[3];
  float* out = (float*)d_out;
  char* ws = (char*)d_ws;
  f16* Xt = (f16*)(ws);
  f16* Qd = (f16*)(ws + 8388608);
  f16* Kd = (f16*)(ws + 16777216);
  f16* Vv = (f16*)(ws + 25165824);

  k_transpose<<<1024, 256, 0, stream>>>(queries, Xt);
  k_proj<<<768, 256, 0, stream>>>(Wq, Wm, Xt, Qd, Kd, Vv);
  k_attn<<<512, 512, 0, stream>>>(Qd, Kd, Vv, mask, out);
}

// Round 7
// 137.295 us; speedup vs baseline: 2.2138x; 1.0238x over previous
//
#include <hip/hip_runtime.h>

#define Bn 2
#define Cn 512
#define Ln 4096
#define Hn 8
#define Dn 64

typedef _Float16 f16;
typedef _Float16 h8 __attribute__((ext_vector_type(8)));
typedef _Float16 h4 __attribute__((ext_vector_type(4)));
typedef float f32x4 __attribute__((ext_vector_type(4)));
typedef float f32x16 __attribute__((ext_vector_type(16)));

#define MFMA32(a, b, c) __builtin_amdgcn_mfma_f32_16x16x32_f16(a, b, c, 0, 0, 0)
#define MFMA3216(a, b, c) __builtin_amdgcn_mfma_f32_32x32x16_f16(a, b, c, 0, 0, 0)
#define AS1(p) ((const __attribute__((address_space(1))) void*)(p))
#define AS3(p) ((__attribute__((address_space(3))) void*)(p))

// ---------------- kernel 1: X [B][C][L] f32 -> Xt [B][L][C] f16 ----------------
__global__ __launch_bounds__(256) void k_transpose(const float* __restrict__ X,
                                                   f16* __restrict__ Xt) {
  int bid = blockIdx.x;
  int b  = bid >> 9;
  int r  = bid & 511;
  int lt = r >> 3, ct = r & 7;
  int l0 = lt << 6, c0 = ct << 6;
  __shared__ f16 t[64][66];
  int tid = threadIdx.x;
  int lx = tid & 63, cg = tid >> 6;
  const float* xb = X + ((size_t)b * Cn) * Ln;
#pragma unroll
  for (int rr = 0; rr < 16; ++rr) {
    int cl = cg * 16 + rr;
    t[lx][cl] = (f16)xb[(size_t)(c0 + cl) * Ln + l0 + lx];
  }
  __syncthreads();
  f16* xo = Xt + ((size_t)b * Ln + l0) * Cn + c0;
  int cx = tid & 63, lg = tid >> 6;
#pragma unroll
  for (int rr = 0; rr < 16; ++rr) {
    int ll = lg * 16 + rr;
    xo[(size_t)ll * Cn + cx] = t[ll][cx];
  }
}

// ---------------- kernel 2: projection GEMM (unchanged) ----------------
__global__ __launch_bounds__(256) void k_proj(const float* __restrict__ Wq,
                                              const float* __restrict__ Wm,
                                              const f16* __restrict__ Xt,
                                              f16* __restrict__ Qd,
                                              f16* __restrict__ Kd,
                                              f16* __restrict__ Vv) {
  int bid = blockIdx.x;
  int b = bid / 384;
  int r = bid % 384;
  int mt = r >> 5, nt = r & 31;
  int o0 = mt << 7, l0 = nt << 7;
  __shared__ f16 a_lds[128][40];
  __shared__ f16 b_lds[128][40];
  int tid = threadIdx.x;
  int lane = tid & 63, w = tid >> 6;
  int wr = w >> 1, wc = w & 1;
  f32x4 acc[4][4] = {};

  int sr = tid >> 1;
  int scg = (tid & 1) << 4;
  int o_s = o0 + sr;
  const float* wrow = (o_s < 512) ? (Wq + (size_t)o_s * Cn)
                                  : (Wm + (size_t)(o_s - 512) * Cn);
  const f16* xrow = Xt + ((size_t)b * Ln + l0 + sr) * Cn;

  for (int kt = 0; kt < 16; ++kt) {
    int c0 = kt << 5;
    __syncthreads();
#pragma unroll
    for (int i = 0; i < 4; ++i) {
      float4 w4 = *(const float4*)(wrow + c0 + scg + 4 * i);
      h4 hh = { (f16)w4.x, (f16)w4.y, (f16)w4.z, (f16)w4.w };
      *(h4*)&a_lds[sr][scg + 4 * i] = hh;
    }
#pragma unroll
    for (int i = 0; i < 2; ++i)
      *(h8*)&b_lds[sr][scg + 8 * i] = *(const h8*)(xrow + c0 + scg + 8 * i);
    __syncthreads();

    h8 af[4], bf[4];
#pragma unroll
    for (int mi = 0; mi < 4; ++mi)
      af[mi] = *(const h8*)&a_lds[wr * 64 + mi * 16 + (lane & 15)][(lane >> 4) * 8];
#pragma unroll
    for (int ni = 0; ni < 4; ++ni)
      bf[ni] = *(const h8*)&b_lds[wc * 64 + ni * 16 + (lane & 15)][(lane >> 4) * 8];
#pragma unroll
    for (int mi = 0; mi < 4; ++mi)
#pragma unroll
      for (int ni = 0; ni < 4; ++ni)
        acc[mi][ni] = MFMA32(af[mi], bf[ni], acc[mi][ni]);
  }

  const float QSCALE = 0.18033688011112042f;   // 2^-3 * log2(e)
  int lrow = (lane >> 4) << 2;
  int lcol = lane & 15;
#pragma unroll
  for (int mi = 0; mi < 4; ++mi) {
    int ob = o0 + wr * 64 + mi * 16 + lrow;
#pragma unroll
    for (int ni = 0; ni < 4; ++ni) {
      int lc = l0 + wc * 64 + ni * 16 + lcol;
      f32x4 a = acc[mi][ni];
      if (ob < 512) {
        int h = ob >> 6, d = ob & 63;
        h4 hh = { (f16)(a[0] * QSCALE), (f16)(a[1] * QSCALE),
                  (f16)(a[2] * QSCALE), (f16)(a[3] * QSCALE) };
        *(h4*)&Qd[(((size_t)b * Hn + h) * Ln + lc) * Dn + d] = hh;
      } else if (ob < 1024) {
        int oc = ob - 512;
        int h = oc >> 6, d = oc & 63;
        h4 hh = { (f16)a[0], (f16)a[1], (f16)a[2], (f16)a[3] };
        *(h4*)&Kd[(((size_t)b * Hn + h) * Ln + lc) * Dn + d] = hh;
      } else {
        int oc = ob - 1024;
#pragma unroll
        for (int rr = 0; rr < 4; ++rr)
          Vv[((size_t)b * Cn + oc + rr) * Ln + lc] = (f16)a[rr];
      }
    }
  }
}

// ---------------- kernel 3: flash attention, 2-way KV split, lean softmax ----------------
// grid 512 (XCD-swizzled), block = 8 waves. Group g: KV half g for same 128 q.
// Softmax: fixed base point (mrow=0) + rs-overflow gate (exact pow2 rescale, ~never).
// pb-build via v_permlane32_swap (no bpermute, no selects).
__global__ __launch_bounds__(512, 4) void k_attn(const f16* __restrict__ Qd,
                                                 const f16* __restrict__ Kd,
                                                 const f16* __restrict__ Vv,
                                                 const int* __restrict__ mask,
                                                 float* __restrict__ out) {
  int bid0 = blockIdx.x;
  int bid = (bid0 & 7) * 64 + (bid0 >> 3);   // T1: 64 blocks (2 bh) per XCD
  int bh = bid >> 5, ib = bid & 31;
  int b = bh >> 3, h = bh & 7;
  int tid = threadIdx.x;
  int lane = tid & 63, w = tid >> 6;
  int grp = w >> 2, wq = w & 3;
  int il = lane & 31, hi = lane >> 5;

  __shared__ __align__(16) f16 smem[8 * 4096];
#define KBUF(g, bi) (&smem[(((g) * 2 + (bi))) * 4096])
#define VBUF(g, bi) (&smem[((4 + (g) * 2 + (bi))) * 4096])

  int qb = ib * 128 + wq * 32;
  const f16* qp = Qd + ((size_t)bh * Ln + qb + il) * Dn;
  h8 qreg[4];
#pragma unroll
  for (int dt = 0; dt < 4; ++dt)
    qreg[dt] = *(const h8*)(qp + dt * 16 + hi * 8);

  // per-64-block all-ones mask flags (all 64 tiles)
  const int* mbase = mask + (size_t)b * Ln;
  unsigned long long flags;
  {
    const int4* mp = (const int4*)mbase + lane * 16;
    int ac = 1;
#pragma unroll
    for (int q = 0; q < 16; ++q) { int4 v = mp[q]; ac &= v.x & v.y & v.z & v.w; }
    flags = __ballot(ac == 1);
  }

  const f16* kbase = Kd + (size_t)bh * Ln * Dn + (size_t)grp * 32 * 4096;
  const f16* vbase = Vv + ((size_t)b * Cn + h * 64) * Ln + grp * 32 * 64;
  int koff[2], voff[2];
#pragma unroll
  for (int q = 0; q < 2; ++q) {
    int rr = wq * 16 + q * 8 + (lane >> 3);
    int swz = (lane & 7) ^ (rr & 7);
    koff[q] = rr * 64 + swz * 8;
    voff[q] = rr * Ln + swz * 8;
  }

#define STAGE(bi, t)                                                            \
  {                                                                             \
    _Pragma("unroll")                                                           \
    for (int q = 0; q < 2; ++q) {                                               \
      __builtin_amdgcn_global_load_lds(AS1(kbase + (size_t)(t) * 4096 + koff[q]),\
                                       AS3(KBUF(grp, bi) + (wq * 16 + q * 8) * 64),\
                                       16, 0, 0);                               \
      __builtin_amdgcn_global_load_lds(AS1(vbase + (size_t)(t) * 64 + voff[q]), \
                                       AS3(VBUF(grp, bi) + (wq * 16 + q * 8) * 64),\
                                       16, 0, 0);                               \
    }                                                                           \
  }

// pack p (f32x16 x2) -> 16 dwords of f16 pairs -> 4 PV B-frags via permlane32_swap
#define PACK_PB(S0_, S1_, DW0_, DW1_, PB_)                                      \
  {                                                                             \
    _Pragma("unroll")                                                           \
    for (int r = 0; r < 16; r += 2) {                                           \
      DW0_[r >> 1] = __builtin_bit_cast(float,                                  \
          __builtin_amdgcn_cvt_pkrtz(S0_[r], S0_[r + 1]));                      \
      DW1_[r >> 1] = __builtin_bit_cast(float,                                  \
          __builtin_amdgcn_cvt_pkrtz(S1_[r], S1_[r + 1]));                      \
    }                                                                           \
    _Pragma("unroll")                                                           \
    for (int jt = 0; jt < 4; ++jt) {                                            \
      float* dd = (jt < 2) ? DW0_ : DW1_;                                       \
      int base = (jt & 1) * 4;                                                  \
      float a0 = dd[base + 0], b0 = dd[base + 2];                               \
      float a1 = dd[base + 1], b1 = dd[base + 3];                               \
      asm("v_permlane32_swap_b32 %0, %1" : "+v"(a0), "+v"(b0));                 \
      asm("v_permlane32_swap_b32 %0, %1" : "+v"(a1), "+v"(b1));                 \
      union { h8 v; float f[4]; } u;                                            \
      u.f[0] = a0; u.f[1] = a1; u.f[2] = b0; u.f[3] = b1;                       \
      PB_[jt] = u.v;                                                            \
    }                                                                           \
  }

  f32x16 acc0 = {}, acc1 = {};  // O^T: col=i=il, row d = dt*32 + (r&3)+8*(r>>2)+4*hi
  float mrow = 0.f;             // fixed base point; bumped only by overflow gate
  float lsum = 0.f;             // HALF-row sum (merged across hi at epilogue)
  int swz7 = il & 7;

  STAGE(0, 0);
  STAGE(1, 1);

#define BODY(t_, waitn_)                                                        \
  {                                                                             \
    asm volatile("s_waitcnt vmcnt(" waitn_ ")" ::: "memory");                   \
    __builtin_amdgcn_s_barrier();                                               \
    const f16* kl_ = KBUF(grp, (t_) & 1);                                       \
    f32x16 s0 = {}, s1 = {};                                                    \
    __builtin_amdgcn_s_setprio(1);                                              \
    _Pragma("unroll")                                                           \
    for (int dt = 0; dt < 4; ++dt) {                                            \
      int c = ((dt * 2 + hi) ^ swz7) << 3;                                      \
      h8 ak0 = *(const h8*)&kl_[il * 64 + c];                                   \
      h8 ak1 = *(const h8*)&kl_[(32 + il) * 64 + c];                            \
      s0 = MFMA3216(ak0, qreg[dt], s0);                                         \
      s1 = MFMA3216(ak1, qreg[dt], s1);                                         \
    }                                                                           \
    __builtin_amdgcn_s_setprio(0);                                              \
    int T_ = grp * 32 + (t_);                                                   \
    if (!((flags >> T_) & 1)) {                                                 \
      _Pragma("unroll")                                                         \
      for (int r = 0; r < 16; ++r) {                                            \
        int j = T_ * 64 + (r & 3) + 8 * (r >> 2) + 4 * hi;                      \
        if (!mbase[j])      s0[r] = -3.0e4f;                                    \
        if (!mbase[j + 32]) s1[r] = -3.0e4f;                                    \
      }                                                                         \
    }                                                                           \
    _Pragma("unroll")                                                           \
    for (int r = 0; r < 16; ++r) {                                              \
      s0[r] = __builtin_amdgcn_exp2f(s0[r] - mrow);                             \
      s1[r] = __builtin_amdgcn_exp2f(s1[r] - mrow);                             \
    }                                                                           \
    float dw0[8], dw1[8];                                                       \
    h8 pb[4];                                                                   \
    PACK_PB(s0, s1, dw0, dw1, pb);                                              \
    float rs;                                                                   \
    {  /* balanced half-row sum tree (no cross-half shuffle) */                 \
      float a0 = (s0[0] + s0[1]) + (s0[2] + s0[3]);                             \
      float a1 = (s0[4] + s0[5]) + (s0[6] + s0[7]);                             \
      float a2 = (s0[8] + s0[9]) + (s0[10] + s0[11]);                           \
      float a3 = (s0[12] + s0[13]) + (s0[14] + s0[15]);                         \
      float a4 = (s1[0] + s1[1]) + (s1[2] + s1[3]);                             \
      float a5 = (s1[4] + s1[5]) + (s1[6] + s1[7]);                             \
      float a6 = (s1[8] + s1[9]) + (s1[10] + s1[11]);                           \
      float a7 = (s1[12] + s1[13]) + (s1[14] + s1[15]);                         \
      rs = ((a0 + a1) + (a2 + a3)) + ((a4 + a5) + (a6 + a7));                   \
    }                                                                           \
    if (__any(rs > 8192.f)) {  /* overflow gate: ~never taken, exact rescale */ \
      float mxp = fmaxf(                                                        \
        fmaxf(fmaxf(fmaxf(s0[0], s0[1]), fmaxf(s0[2], s0[3])),                  \
              fmaxf(fmaxf(s0[4], s0[5]), fmaxf(s0[6], s0[7]))),                 \
        fmaxf(fmaxf(fmaxf(s0[8], s0[9]), fmaxf(s0[10], s0[11])),                \
              fmaxf(fmaxf(s0[12], s0[13]), fmaxf(s0[14], s0[15]))));            \
      float mxq = fmaxf(                                                        \
        fmaxf(fmaxf(fmaxf(s1[0], s1[1]), fmaxf(s1[2], s1[3])),                  \
              fmaxf(fmaxf(s1[4], s1[5]), fmaxf(s1[6], s1[7]))),                 \
        fmaxf(fmaxf(fmaxf(s1[8], s1[9]), fmaxf(s1[10], s1[11])),                \
              fmaxf(fmaxf(s1[12], s1[13]), fmaxf(s1[14], s1[15]))));            \
      mxp = fmaxf(mxp, mxq);                                                    \
      mxp = fmaxf(mxp, __shfl_xor(mxp, 32));  /* row-uniform */                 \
      int e = (((__builtin_bit_cast(int, mxp) >> 23) & 255) - 127) - 3;         \
      float sc = __builtin_bit_cast(float, (127 - e) << 23);  /* 2^-e exact */  \
      mrow += (float)e;                                                         \
      _Pragma("unroll")                                                         \
      for (int r = 0; r < 16; ++r) {                                            \
        s0[r] *= sc; s1[r] *= sc;                                               \
        acc0[r] *= sc; acc1[r] *= sc;                                           \
      }                                                                         \
      lsum *= sc; rs *= sc;                                                     \
      PACK_PB(s0, s1, dw0, dw1, pb);                                            \
    }                                                                           \
    lsum += rs;                                                                 \
    const f16* vl_ = VBUF(grp, (t_) & 1);                                       \
    __builtin_amdgcn_s_setprio(1);                                              \
    _Pragma("unroll")                                                           \
    for (int dt = 0; dt < 2; ++dt) {                                            \
      int rv = dt * 32 + il;                                                    \
      _Pragma("unroll")                                                         \
      for (int jt = 0; jt < 4; ++jt) {                                          \
        h8 av = *(const h8*)&vl_[rv * 64 + (((jt * 2 + hi) ^ swz7) << 3)];      \
        if (dt == 0) acc0 = MFMA3216(av, pb[jt], acc0);                         \
        else         acc1 = MFMA3216(av, pb[jt], acc1);                         \
      }                                                                         \
    }                                                                           \
    __builtin_amdgcn_s_setprio(0);                                              \
    __builtin_amdgcn_s_barrier();                                               \
    if ((t_) < 30) STAGE((t_) & 1, (t_) + 2);                                   \
  }

  for (int t = 0; t < 31; ++t) {
    BODY(t, "4");
  }
  BODY(31, "0");

  // full-row lsum (lanes i and i+32 hold halves)
  lsum += __shfl_xor(lsum, 32);

  // ---- merge the two KV halves via LDS (padded stride-33 to dodge conflicts) ----
  __syncthreads();
  float* shf = (float*)smem;
  if (grp == 1) {
    float* basep = shf + wq * (64 * 33) + lane * 33;
#pragma unroll
    for (int r = 0; r < 16; ++r) { basep[r] = acc0[r]; basep[16 + r] = acc1[r]; }
    float* ml = shf + 4 * 64 * 33 + (wq * 64 + lane) * 2;
    ml[0] = mrow; ml[1] = lsum;
  }
  __syncthreads();
  if (grp == 0) {
    float* basep = shf + wq * (64 * 33) + lane * 33;
    float* ml = shf + 4 * 64 * 33 + (wq * 64 + lane) * 2;
    float mB = ml[0], lB = ml[1];
    float M = fmaxf(mrow, mB);
    float wA = __builtin_amdgcn_exp2f(mrow - M);
    float wB = __builtin_amdgcn_exp2f(mB - M);
    float linv = 1.f / fmaxf(lsum * wA + lB * wB, 1e-30f);
    float fA = wA * linv, fB = wB * linv;
    size_t obase = ((size_t)b * Cn + h * 64) * Ln + qb + il;
#pragma unroll
    for (int r = 0; r < 16; ++r) {
      int d0 = (r & 3) + 8 * (r >> 2) + 4 * hi;
      out[obase + (size_t)d0 * Ln] = acc0[r] * fA + basep[r] * fB;
      out[obase + (size_t)(d0 + 32) * Ln] = acc1[r] * fA + basep[16 + r] * fB;
    }
  }
}

extern "C" void kernel_launch(void* const* d_in, const int* in_sizes, int n_in,
                              void* d_out, int out_size, void* d_ws, size_t ws_size,
                              hipStream_t stream) {
  const float* queries = (const float*)d_in[0];
  const int*   mask    = (const int*)d_in[1];
  const float* Wm      = (const float*)d_in[2];
  const float* Wq      = (const float*)d_in[3];
  float* out = (float*)d_out;
  char* ws = (char*)d_ws;
  f16* Xt = (f16*)(ws);
  f16* Qd = (f16*)(ws + 8388608);
  f16* Kd = (f16*)(ws + 16777216);
  f16* Vv = (f16*)(ws + 25165824);

  k_transpose<<<1024, 256, 0, stream>>>(queries, Xt);
  k_proj<<<768, 256, 0, stream>>>(Wq, Wm, Xt, Qd, Kd, Vv);
  k_attn<<<512, 512, 0, stream>>>(Qd, Kd, Vv, mask, out);
}